// Round 8
// baseline (790.959 us; speedup 1.0000x reference)
//
#include <hip/hip_runtime.h>
#include <math.h>

#define BATCH 32
#define TSEQ  4096
#define HD    128
#define NST   128
#define BT    (BATCH*TSEQ)     // 131072
#define LC    64               // scan chunk length
#define NCHK  (TSEQ/LC)        // 64 chunks

typedef unsigned short bf16;
typedef __attribute__((ext_vector_type(8))) short bf16x8;   // 8 bf16 = 4 VGPRs (MFMA A/B frag)
typedef __attribute__((ext_vector_type(4))) float f32x4;    // MFMA C/D frag

// sigma: storage index j -> true index h
//   sigma(j) = (j[6:5]<<5) | (j[3:2]<<3) | (j[4]<<2) | j[1:0]
//   inv(h): position j such that sigma(j)=h
__device__ __host__ inline int sig_f(int j) {
    return ((j >> 5) << 5) | (((j >> 2) & 3) << 3) | (((j >> 4) & 1) << 2) | (j & 3);
}
__device__ __host__ inline int inv_f(int h) {
    return ((h >> 5) << 5) | (((h >> 2) & 1) << 4) | (((h >> 3) & 3) << 2) | (h & 3);
}

__device__ inline float bf2f(bf16 s) {
    union { unsigned int u; float f; } v; v.u = ((unsigned int)s) << 16; return v.f;
}
__device__ inline bf16 f2bf(float f) {
    union { float f; unsigned int u; } v; v.f = f;
    unsigned int u = v.u;
    unsigned int r = (u + 0x7fffu + ((u >> 16) & 1u)) >> 16;
    return (bf16)r;
}
// pack two f32 -> bf16 pair (round-half-up) in ~3 VALU via v_perm
__device__ inline unsigned int pkpair(float lo, float hi) {
    union { float f; unsigned int u; } a, b;
    a.f = lo; b.f = hi;
    return __builtin_amdgcn_perm(b.u + 0x8000u, a.u + 0x8000u, 0x07060302u);
}
__device__ inline bf16x8 pack8f(float4 f0, float4 f1) {
    union { bf16x8 v; unsigned int u[4]; } t;
    t.u[0] = pkpair(f0.x, f0.y);
    t.u[1] = pkpair(f0.z, f0.w);
    t.u[2] = pkpair(f1.x, f1.y);
    t.u[3] = pkpair(f1.z, f1.w);
    return t.v;
}
__device__ inline float2 cmul2(float2 a, float2 b) {
    return make_float2(a.x*b.x - a.y*b.y, a.x*b.y + a.y*b.x);
}
// tanh-form gelu: max |diff vs exact erf-gelu| ~1e-3, under bf16 noise here
__device__ inline float gelu_f(float x) {
    float u = x*(0.7978845608f + 0.0356774081f*x*x);
    return __fdividef(x, 1.f + __expf(-2.f*u));
}
__device__ inline float2 upk(unsigned int w) {     // bf16 pair -> fp32 pair
    union { unsigned int u; float f; } a, b;
    a.u = w << 16; b.u = w & 0xffff0000u;
    return make_float2(a.f, b.f);
}
__device__ inline unsigned int pk(float2 x) { return pkpair(x.x, x.y); }

// ---------------- S5 param prep: g-folded W'bu, S/bias, Wc(sigma rows), ... ----------
// Xbf lives in SIGMA-column layout after layer-1 s5mlp. Hence:
//   - Wc rows sigma-permuted (storage row j holds true h=sigma(j)) -> s5mlp phase-A
//     output lands in hpx layout that directly feeds GEMM1.
//   - Wbu columns: true for i=0 (x_in is true-layout), sigma-permuted for i=1.
__global__ void prep_s5(const float* __restrict__ Lam_re, const float* __restrict__ Lam_im,
                        const float* __restrict__ B_re,  const float* __restrict__ B_im,
                        const float* __restrict__ C_re,  const float* __restrict__ C_im,
                        const float* __restrict__ log_step,
                        const float* __restrict__ ln1_g, const float* __restrict__ ln1_b,
                        const float* __restrict__ D_skip,
                        bf16* __restrict__ Wbu_bf,  // [2][256][128], row 2n=Re 2n+1=Im, g-folded
                        bf16* __restrict__ Wc_bf,   // [2][128][256], sigma rows
                        float* __restrict__ Sb, float* __restrict__ biasb,   // [2][256]
                        float* __restrict__ gd, float* __restrict__ bd,      // [2][128]
                        float4* __restrict__ coefs,
                        float2* __restrict__ apow)  // [2][64][128]: apow[i][j][n] = a^(j+1)
{
    int i = blockIdx.x, n = threadIdx.x;
    int in = i*NST + n;
    float lr = Lam_re[in], li = Lam_im[in];
    float dt = expf(log_step[in]);
    float ea = expf(lr*dt);
    float ar = ea*cosf(li*dt), ai = ea*sinf(li*dt);
    float xx = ar - 1.f, yy = ai;
    float den = lr*lr + li*li;
    float sr = (xx*lr + yy*li)/den;
    float si = (yy*lr - xx*li)/den;
    float2 a2 = make_float2(ar, ai);
    float2 p = a2;
    float2* apr = apow + (size_t)i*64*128;
    for (int j = 0; j < 64; ++j) {     // apow[j][n] = a^(j+1)
        apr[j*128 + n] = p;
        p = cmul2(p, a2);
    }
    // recompute a^64 via repeated squaring for exactness
    float2 q = a2;
    #pragma unroll
    for (int t = 0; t < 6; ++t) q = cmul2(q, q);
    coefs[in] = make_float4(ar, ai, q.x, q.y);

    const float* g  = ln1_g + i*HD;
    const float* bb = ln1_b + i*HD;
    const float* br = B_re + (size_t)in*HD;
    const float* bi = B_im + (size_t)in*HD;
    bf16* wb = Wbu_bf + (size_t)i*256*128;
    float s_re = 0.f, s_im = 0.f, bc_re = 0.f, bc_im = 0.f;
    for (int h = 0; h < HD; ++h) {
        float wre = sr*br[h] - si*bi[h];
        float wim = sr*bi[h] + si*br[h];
        bf16 wrb = f2bf(g[h]*wre), wib = f2bf(g[h]*wim);
        int hc = (i == 0) ? h : inv_f(h);   // i=1 consumes sigma-layout Xbf
        wb[(2*n)*128 + hc]   = wrb;
        wb[(2*n+1)*128 + hc] = wib;
        s_re += bf2f(wrb); s_im += bf2f(wib);
        bc_re += bb[h]*wre; bc_im += bb[h]*wim;
    }
    Sb[i*256 + 2*n] = s_re;     Sb[i*256 + 2*n+1] = s_im;
    biasb[i*256 + 2*n] = bc_re; biasb[i*256 + 2*n+1] = bc_im;

    const float* cr = C_re + (size_t)i*HD*NST;
    const float* ci = C_im + (size_t)i*HD*NST;
    bf16* wc = Wc_bf + (size_t)i*128*256;
    for (int h = 0; h < HD; ++h) {
        int jr = inv_f(h);                  // sigma rows
        wc[jr*256 + 2*n]   = f2bf( 2.f * cr[h*NST + n]);
        wc[jr*256 + 2*n+1] = f2bf(-2.f * ci[h*NST + n]);
    }
    gd[i*HD + n] = g[n]*D_skip[i*HD + n];
    bd[i*HD + n] = bb[n]*D_skip[i*HD + n];
}

// W1 -> g2-folded bf16, f-rows sigma-permuted (HW-verified R2-R7):
//   row j holds true f = sigma(j); GEMM1 D then packs directly into GEMM2 A-frags.
// K-columns (h) stay TRUE (double-sigma cancellation). S1/bias1p true-f-indexed.
__global__ void prep_w1(const float* __restrict__ W1, const float* __restrict__ b1,
                        const float* __restrict__ ln2_g, const float* __restrict__ ln2_b,
                        bf16* __restrict__ W1_bf, float* __restrict__ S1,
                        float* __restrict__ bias1p)
{
    int i = blockIdx.x, f = threadIdx.x;       // f in [0,256) true feature
    const float* g  = ln2_g + i*HD;
    const float* bb = ln2_b + i*HD;
    bf16* w = W1_bf + (size_t)i*256*128;
    int j = ((f >> 5) << 5) | (((f >> 2) & 1) << 4) | (((f >> 3) & 3) << 2) | (f & 3);
    float S = 0.f, bi_ = b1[i*256 + f];
    for (int h = 0; h < HD; ++h) {
        float wv = W1[(size_t)i*32768 + h*256 + f];
        bf16 wbv = f2bf(g[h]*wv);
        w[j*128 + h] = wbv;
        S += bf2f(wbv);
        bi_ += bb[h]*wv;
    }
    S1[i*256 + f] = S;
    bias1p[i*256 + f] = bi_;
}

// W2 -> bf16 transposed [h][f], h-rows SIGMA-permuted: storage row j holds true
// h=sigma(j). Phase-C output columns then align pairwise with hpx (residual in regs)
// and stores land at plain n0 positions of sigma-layout Xbf.
__global__ void prep_w2(const float* __restrict__ W2, bf16* __restrict__ W2_bf)
{
    int i = blockIdx.x, h = threadIdx.x;       // h in [0,128) true
    bf16* w = W2_bf + (size_t)i*128*256 + (size_t)inv_f(h)*256;
    for (int f = 0; f < 256; ++f)
        w[f] = f2bf(W2[(size_t)i*32768 + f*128 + h]);
}

// conv weights [c][ic][tap] -> bf16 [c][tap*128+icj]; conv1 consumes sigma-layout Xbf,
// so wB1 stores at position icj the weight of true channel sigma(icj). wB2 true.
__global__ void prep_wB(const float* __restrict__ w1, const float* __restrict__ w2,
                        bf16* __restrict__ wB1, bf16* __restrict__ wB2)
{
    int idx = blockIdx.x*256 + threadIdx.x;
    if (idx >= 163840) return;
    int r   = idx % 81920;
    int c   = r / 640;
    int tap = (r % 640) / 128;
    int icj = r % 128;
    if (idx < 81920) {
        wB1[r] = f2bf(w1[(c*128 + sig_f(icj))*5 + tap]);
    } else {
        wB2[r] = f2bf(w2[(c*128 + icj)*5 + tap]);
    }
}

// ---------------- fused LN + GEMM (K=128, N=256), bf16 out, 2 strips/wave ------------
// Operand-swapped MFMA: lane cl owns output row t directly. Stores per-row (mu,rs).
template<typename TA>
__global__ __launch_bounds__(512, 2) void lngemm2(
    const TA* __restrict__ A,          // [BT,128] fp32 (true) or bf16 (sigma; Wbu matches)
    const bf16* __restrict__ Bt,       // [256][128] g-folded
    const float* __restrict__ Svec, const float* __restrict__ bvec,  // [256]
    bf16* __restrict__ outB,           // [BT,256]
    float2* __restrict__ munrs)        // [BT]
{
    __shared__ bf16 Bs[256*136];       // 69632 B (+8 pad per row)
    __shared__ float Sl[256], bl[256];

    int tid = threadIdx.x;
    #pragma unroll
    for (int it = 0; it < 8; ++it) {
        int f = it*512 + tid;
        int n = f >> 4, kk = (f & 15)*8;
        *(bf16x8*)&Bs[n*136 + kk] = *(const bf16x8*)(Bt + n*128 + kk);
    }
    if (tid < 256) { Sl[tid] = Svec[tid]; bl[tid] = bvec[tid]; }
    __syncthreads();

    int wid = tid >> 6, lane = tid & 63;
    int quad = lane >> 4, cl = lane & 15;
    int s0 = blockIdx.x*16 + wid*2;
    size_t row0 = (size_t)s0*16 + cl;          // strip p -> row0 + p*16

    bf16x8 af[2][4];
    float mu[2], rs[2], mr[2];
    #pragma unroll
    for (int p = 0; p < 2; ++p) {
        size_t row = row0 + (size_t)p*16;
        float sm = 0.f, sq = 0.f;
        if constexpr (sizeof(TA) == 2) {
            const bf16* ar = (const bf16*)A + row*128;
            #pragma unroll
            for (int ks = 0; ks < 4; ++ks) {
                af[p][ks] = *(const bf16x8*)(ar + quad*8 + ks*32);
                union { bf16x8 v; unsigned int u[4]; } aa; aa.v = af[p][ks];
                #pragma unroll
                for (int jp = 0; jp < 4; ++jp) {
                    float2 vv = upk(aa.u[jp]);
                    sm += vv.x + vv.y;
                    sq += vv.x*vv.x + vv.y*vv.y;
                }
            }
        } else {
            const float* ar = (const float*)A + row*128;
            #pragma unroll
            for (int ks = 0; ks < 4; ++ks) {
                float4 f0 = *(const float4*)(ar + quad*8 + ks*32);
                float4 f1 = *(const float4*)(ar + quad*8 + ks*32 + 4);
                sm += f0.x + f0.y + f0.z + f0.w + f1.x + f1.y + f1.z + f1.w;
                sq += f0.x*f0.x + f0.y*f0.y + f0.z*f0.z + f0.w*f0.w
                    + f1.x*f1.x + f1.y*f1.y + f1.z*f1.z + f1.w*f1.w;
                af[p][ks] = pack8f(f0, f1);
            }
        }
        sm += __shfl_xor(sm, 16); sm += __shfl_xor(sm, 32);
        sq += __shfl_xor(sq, 16); sq += __shfl_xor(sq, 32);
        mu[p] = sm * (1.f/128.f);
        rs[p] = rsqrtf(sq*(1.f/128.f) - mu[p]*mu[p] + 1e-5f);
        mr[p] = mu[p]*rs[p];
        if (quad == 0) munrs[row] = make_float2(mu[p], rs[p]);
    }

    #pragma unroll
    for (int g = 0; g < 4; ++g) {
        f32x4 acc0[4] = {}, acc1[4] = {};
        #pragma unroll
        for (int t4 = 0; t4 < 4; ++t4) {
            const bf16* wrp = &Bs[(((g*4+t4)*16) + cl)*136 + quad*8];
            #pragma unroll
            for (int ks = 0; ks < 4; ++ks) {
                bf16x8 w = *(const bf16x8*)(wrp + ks*32);
                acc0[t4] = __builtin_amdgcn_mfma_f32_16x16x32_bf16(w, af[0][ks], acc0[t4], 0, 0, 0);
                acc1[t4] = __builtin_amdgcn_mfma_f32_16x16x32_bf16(w, af[1][ks], acc1[t4], 0, 0, 0);
            }
        }
        #pragma unroll
        for (int t4 = 0; t4 < 4; ++t4) {
            int n0 = (g*4+t4)*16 + quad*4;
            float4 S4 = *(const float4*)&Sl[n0];
            float4 b4 = *(const float4*)&bl[n0];
            float4 o;
            o.x = rs[0]*acc0[t4][0] - mr[0]*S4.x + b4.x;
            o.y = rs[0]*acc0[t4][1] - mr[0]*S4.y + b4.y;
            o.z = rs[0]*acc0[t4][2] - mr[0]*S4.z + b4.z;
            o.w = rs[0]*acc0[t4][3] - mr[0]*S4.w + b4.w;
            *(uint2*)(outB + row0*256 + n0) = make_uint2(pkpair(o.x, o.y), pkpair(o.z, o.w));
            o.x = rs[1]*acc1[t4][0] - mr[1]*S4.x + b4.x;
            o.y = rs[1]*acc1[t4][1] - mr[1]*S4.y + b4.y;
            o.z = rs[1]*acc1[t4][2] - mr[1]*S4.z + b4.z;
            o.w = rs[1]*acc1[t4][3] - mr[1]*S4.w + b4.w;
            *(uint2*)(outB + (row0+16)*256 + n0) = make_uint2(pkpair(o.x, o.y), pkpair(o.z, o.w));
        }
    }
}

// ---------------- fused S5-epilogue + MLP, single time-shared weight buffer ----------
// R7 post-mortem: no spill but 138KB LDS -> 1 blk/CU -> 8 waves/CU -> latency-dead
// (140us, all pipes <30%). Fix: ONE 68KB buffer serves all 3 GEMMs --
// [128][264] (Wc) == [256][132] (W1) == [128][264] (W2), all 67584 B.
// Wc staged upfront; W1 and W2 re-staged from global (L2-resident) through
// short-lived regs between phases. LDS 71KB -> 2 blocks/CU -> 16 waves/CU,
// cross-block overlap hides the per-block barriers.
// launch_bounds(512,4): 4 waves/EU -> 2 blocks/CU, VGPR cap 128 (R7: fits, no spill).
// hpx (phase-A bf16 out) == GEMM1 A-frags; hp1 == GEMM2 A-frags (sigma-construction);
// phase-C cols align with hpx for residual; stores at n0 => Xbf in sigma layout.
template<int FIRST>
__global__ __launch_bounds__(512, 4) void s5mlp(
    const bf16* __restrict__ A,        // [BT,256] Cbuf (post local scan)
    const void* resid,                 // [BT,128] fp32 true (FIRST) / bf16 sigma
    bf16* out,                         // [BT,128] sigma layout (may alias resid)
    const float2* __restrict__ munrs,
    const float* __restrict__ gdp, const float* __restrict__ bdp,   // true-h
    const float2* __restrict__ carry,  // [NCHK][B][128]
    const float2* __restrict__ apow,   // [64][128]
    const bf16* __restrict__ Wcp,      // [128][256] sigma rows
    const bf16* __restrict__ W1p,      // [256][128] sigma f-rows
    const bf16* __restrict__ W2p,      // [128][256] sigma h-rows
    const float* __restrict__ S1v, const float* __restrict__ b1v,   // [256] true-f
    const float* __restrict__ b2v)     // [128] true-h
{
    __shared__ bf16 Wl[128*264];       // 67584 B, time-shared: Wc -> W1 -> W2
    __shared__ float gdl[128], bdl[128], S1l[256], b1l[256], b2l[128];

    int tid = threadIdx.x;
    #pragma unroll
    for (int it = 0; it < 8; ++it) {   // Wc -> Wl as [128][264]
        int f = it*512 + tid;
        int n = f >> 5, kk = (f & 31)*8;
        *(bf16x8*)&Wl[n*264 + kk] = *(const bf16x8*)(Wcp + n*256 + kk);
    }
    if (tid < 128)      { gdl[tid] = gdp[tid]; bdl[tid] = bdp[tid]; }
    else if (tid < 384) { S1l[tid-128] = S1v[tid-128]; b1l[tid-128] = b1v[tid-128]; }
    else                { b2l[tid-384] = b2v[tid-384]; }
    __syncthreads();

    int wid = tid >> 6, lane = tid & 63;
    int quad = lane >> 4, cl = lane & 15;
    int s = blockIdx.x*8 + wid;
    size_t row = (size_t)s*16 + cl;

    float2 m2 = munrs[row];
    float mu = m2.x, rs = m2.y;

    // A-frags from Cbuf + fused cross-chunk scan fix
    bf16x8 af[8];
    {
        const bf16* ar = A + row*256 + quad*8;
        int b  = (int)(row >> 12);
        int tp = (int)(row & 4095);
        int cc = tp >> 6, j = tp & 63;
        const float2* cin = carry + (size_t)cc*(BATCH*NST) + (size_t)b*NST;
        const float2* ap  = apow + (size_t)j*128;
        #pragma unroll
        for (int ks = 0; ks < 8; ++ks) {
            union { bf16x8 v; unsigned int u[4]; } t;
            t.v = *(const bf16x8*)(ar + ks*32);
            int n0c = quad*4 + ks*16;
            #pragma unroll
            for (int jp = 0; jp < 4; ++jp) {
                float2 v  = upk(t.u[jp]);
                float2 ad = cmul2(ap[n0c+jp], cin[n0c+jp]);
                t.u[jp] = pk(make_float2(v.x + ad.x, v.y + ad.y));
            }
            af[ks] = t.v;
        }
    }

    // ---- phase A: Wc GEMM (sigma rows); per-nt acc retired immediately ----
    union { unsigned int u[8][2]; bf16x8 v[4]; } hpx;
    #pragma unroll
    for (int nt = 0; nt < 8; ++nt) {
        const bf16* wrp = &Wl[(nt*16 + cl)*264 + quad*8];
        f32x4 a0 = {};
        #pragma unroll
        for (int ks = 0; ks < 8; ++ks)
            a0 = __builtin_amdgcn_mfma_f32_16x16x32_bf16(
                     *(const bf16x8*)(wrp + ks*32), af[ks], a0, 0, 0, 0);
        int fb = ((nt >> 1) << 5) + (quad << 3) + ((nt & 1) << 2);  // true-h base
        float4 rv;
        if constexpr (FIRST) {
            rv = *(const float4*)((const float*)resid + row*128 + fb);
        } else {
            int n0 = nt*16 + quad*4;          // sigma-layout position
            ushort4 u4 = *(const ushort4*)((const bf16*)resid + row*128 + n0);
            rv = make_float4(bf2f(u4.x), bf2f(u4.y), bf2f(u4.z), bf2f(u4.w));
        }
        float4 g4 = *(const float4*)&gdl[fb];
        float4 b4 = *(const float4*)&bdl[fb];
        float4 o;
        o.x = rv.x + a0[0] + (rv.x - mu)*rs*g4.x + b4.x;
        o.y = rv.y + a0[1] + (rv.y - mu)*rs*g4.y + b4.y;
        o.z = rv.z + a0[2] + (rv.z - mu)*rs*g4.z + b4.z;
        o.w = rv.w + a0[3] + (rv.w - mu)*rs*g4.w + b4.w;
        hpx.u[nt][0] = pkpair(o.x, o.y);
        hpx.u[nt][1] = pkpair(o.z, o.w);
    }

    __syncthreads();                   // all waves done reading Wc

    // ---- stage W1 -> regs (LN2 stats overlap the load latency) -> Wl [256][132] ----
    bf16x8 w1r[8];
    #pragma unroll
    for (int it = 0; it < 8; ++it) {
        int f = it*512 + tid;
        w1r[it] = *(const bf16x8*)(W1p + (size_t)(f >> 4)*128 + (f & 15)*8);
    }

    // LN2 stats on hpx (VALU + shfl; overlaps W1 load latency)
    float sm = 0.f, sq = 0.f;
    #pragma unroll
    for (int nt = 0; nt < 8; ++nt)
        #pragma unroll
        for (int e = 0; e < 2; ++e) {
            float2 vv = upk(hpx.u[nt][e]);
            sm += vv.x + vv.y;
            sq += vv.x*vv.x + vv.y*vv.y;
        }
    sm += __shfl_xor(sm, 16); sm += __shfl_xor(sm, 32);
    sq += __shfl_xor(sq, 16); sq += __shfl_xor(sq, 32);
    float mu2 = sm * (1.f/128.f);
    float rs2 = rsqrtf(sq*(1.f/128.f) - mu2*mu2 + 1e-5f);
    float mr2 = mu2*rs2;

    #pragma unroll
    for (int it = 0; it < 8; ++it) {
        int f = it*512 + tid;
        *(bf16x8*)&Wl[(f >> 4)*132 + (f & 15)*8] = w1r[it];
    }
    __syncthreads();                   // W1 visible

    // ---- issue W2 loads (held through phase B; latency hidden under MFMAs) ----
    bf16x8 w2r[8];
    #pragma unroll
    for (int it = 0; it < 8; ++it) {
        int f = it*512 + tid;
        w2r[it] = *(const bf16x8*)(W2p + (size_t)(f >> 5)*256 + (f & 31)*8);
    }

    // ---- phase B: W1 GEMM + gelu -> hp1 (reads Wl as [256][132]) ----
    union { unsigned int u[16][2]; bf16x8 v[8]; } hp1;
    #pragma unroll
    for (int half = 0; half < 2; ++half) {
        #pragma unroll
        for (int nt = 0; nt < 8; ++nt) {
            int NT = half*8 + nt;
            const bf16* wrp = &Wl[((NT*16) + cl)*132 + quad*8];
            f32x4 a0 = {};
            #pragma unroll
            for (int ks = 0; ks < 4; ++ks)
                a0 = __builtin_amdgcn_mfma_f32_16x16x32_bf16(
                         *(const bf16x8*)(wrp + ks*32), hpx.v[ks], a0, 0, 0, 0);
            int fb = ((NT >> 1) << 5) + (quad << 3) + ((NT & 1) << 2);  // true-f base
            float4 S4 = *(const float4*)&S1l[fb];
            float4 b4 = *(const float4*)&b1l[fb];
            float4 o;
            o.x = gelu_f(rs2*a0[0] - mr2*S4.x + b4.x);
            o.y = gelu_f(rs2*a0[1] - mr2*S4.y + b4.y);
            o.z = gelu_f(rs2*a0[2] - mr2*S4.z + b4.z);
            o.w = gelu_f(rs2*a0[3] - mr2*S4.w + b4.w);
            hp1.u[NT][0] = pkpair(o.x, o.y);
            hp1.u[NT][1] = pkpair(o.z, o.w);
        }
    }

    __syncthreads();                   // all waves done reading W1
    #pragma unroll
    for (int it = 0; it < 8; ++it) {   // W2 regs -> Wl as [128][264]
        int f = it*512 + tid;
        *(bf16x8*)&Wl[(f >> 5)*264 + (f & 31)*8] = w2r[it];
    }
    __syncthreads();                   // W2 visible

    // ---- phase C: W2 GEMM (sigma rows); + b2 + resid(hpx) -> store (sigma layout) ---
    #pragma unroll
    for (int nt = 0; nt < 8; ++nt) {
        const bf16* wrp = &Wl[(nt*16 + cl)*264 + quad*8];
        f32x4 a0 = {};
        #pragma unroll
        for (int ks = 0; ks < 8; ++ks)
            a0 = __builtin_amdgcn_mfma_f32_16x16x32_bf16(
                     *(const bf16x8*)(wrp + ks*32), hp1.v[ks], a0, 0, 0, 0);
        int fb = ((nt >> 1) << 5) + (quad << 3) + ((nt & 1) << 2);  // true-h base
        int n0 = nt*16 + quad*4;                                    // sigma position
        float4 b4 = *(const float4*)&b2l[fb];
        float2 r01 = upk(hpx.u[nt][0]);
        float2 r23 = upk(hpx.u[nt][1]);
        float4 o;
        o.x = a0[0] + b4.x + r01.x;
        o.y = a0[1] + b4.y + r01.y;
        o.z = a0[2] + b4.z + r23.x;
        o.w = a0[3] + b4.w + r23.y;
        *(uint2*)(out + row*128 + n0) = make_uint2(pkpair(o.x, o.y), pkpair(o.z, o.w));
    }
}

// ---------------- chunked scan on bf16-pair xs: x_t = a*x_{t-1} + Bu_t ---------------
// Local pass only; cross-chunk fix is fused into s5mlp. 2 states/thread (uint2, 8B/lane;
// R3 best-total config).
__global__ __launch_bounds__(256) void scan_local(uint2* __restrict__ xs,
                                                  const float4* __restrict__ coefs,
                                                  float2* __restrict__ carry)
{
    int flat = blockIdx.x*256 + threadIdx.x;  // 2^17
    int n2 = flat & 63;                        // handles states 2*n2, 2*n2+1
    int b = (flat >> 6) & 31;
    int c = flat >> 11;
    float4 cf0 = coefs[2*n2], cf1 = coefs[2*n2+1];
    float2 a0 = make_float2(cf0.x, cf0.y);
    float2 a1 = make_float2(cf1.x, cf1.y);
    uint2* base = xs + ((size_t)(b*TSEQ + c*LC))*64 + n2;
    float2 x0 = make_float2(0.f, 0.f), x1 = make_float2(0.f, 0.f);
    for (int j = 0; j < LC; ++j) {
        uint2 v = base[(size_t)j*64];
        float2 v0 = upk(v.x), v1 = upk(v.y);
        x0 = make_float2(a0.x*x0.x - a0.y*x0.y + v0.x, a0.x*x0.y + a0.y*x0.x + v0.y);
        x1 = make_float2(a1.x*x1.x - a1.y*x1.y + v1.x, a1.x*x1.y + a1.y*x1.x + v1.y);
        base[(size_t)j*64] = make_uint2(pk(x0), pk(x1));
    }
    carry[c*(BATCH*NST) + b*NST + 2*n2]   = x0;
    carry[c*(BATCH*NST) + b*NST + 2*n2+1] = x1;
}

__global__ void scan_carry(float2* __restrict__ carry, const float4* __restrict__ coefs)
{
    int flat = blockIdx.x*256 + threadIdx.x;  // 4096 = B*N
    int n = flat & 127;
    float4 cf = coefs[n];
    float2 aL = make_float2(cf.z, cf.w);
    float2 x = make_float2(0.f, 0.f);
    for (int c = 0; c < NCHK; ++c) {
        float2* p = carry + c*(BATCH*NST) + flat;
        float2 v = *p;
        *p = x;                                // exclusive prefix
        x = make_float2(aL.x*x.x - aL.y*x.y + v.x, aL.x*x.y + aL.y*x.x + v.y);
    }
}

// ---------------- conv1: bf16 in (sigma channels; weights pre-permuted), MFMA --------
__global__ __launch_bounds__(256, 4) void conv1_mfma(
    const bf16* __restrict__ X,
    const bf16* __restrict__ wB,    // [128][640]
    const float* __restrict__ bias,
    bf16* __restrict__ out,         // [B*Lout][128]
    int Tin, int Lout)
{
    __shared__ bf16 As[128][72];
    __shared__ bf16 Bs[128][72];
    int tid  = threadIdx.x;
    int lane = tid & 63;
    int wave = tid >> 6;
    int wm = wave >> 1, wn = wave & 1;
    int quad = lane >> 4, cl = lane & 15;
    int row0 = blockIdx.x * 128;
    int b  = row0 / Lout;
    int l0 = row0 % Lout;
    const bf16* Xb = X + (size_t)b*Tin*128;

    f32x4 acc[4][4] = {};

    for (int k0 = 0; k0 < 640; k0 += 64) {
        int tap = k0 / 128;
        int icb = k0 % 128;
        #pragma unroll
        for (int it = 0; it < 4; ++it) {
            int idx = it*256 + tid;
            int r = idx >> 3, kof = (idx & 7) * 8;
            int t = 2*(l0 + r) - 2 + tap;
            bf16x8 z = {0,0,0,0,0,0,0,0};
            if (t >= 0 && t < Tin) z = *(const bf16x8*)(Xb + (size_t)t*128 + icb + kof);
            *(bf16x8*)&As[r][kof] = z;
        }
        #pragma unroll
        for (int it = 0; it < 4; ++it) {
            int idx = it*256 + tid;
            int n = idx >> 3, kof = (idx & 7) * 8;
            *(bf16x8*)&Bs[n][kof] = *(const bf16x8*)(wB + (size_t)n*640 + k0 + kof);
        }
        __syncthreads();
        #pragma unroll
        for (int kk = 0; kk < 64; kk += 32) {
            bf16x8 af[4], bfr[4];
            #pragma unroll
            for (int i = 0; i < 4; ++i)
                af[i] = *(const bf16x8*)&As[wm*64 + i*16 + cl][kk + quad*8];
            #pragma unroll
            for (int j = 0; j < 4; ++j)
                bfr[j] = *(const bf16x8*)&Bs[wn*64 + j*16 + cl][kk + quad*8];
            #pragma unroll
            for (int i = 0; i < 4; ++i)
                #pragma unroll
                for (int j = 0; j < 4; ++j)
                    acc[i][j] = __builtin_amdgcn_mfma_f32_16x16x32_bf16(
                                    bfr[j], af[i], acc[i][j], 0, 0, 0);
        }
        __syncthreads();
    }

    #pragma unroll
    for (int i = 0; i < 4; ++i) {
        int grow = row0 + wm*64 + i*16 + cl;
        #pragma unroll
        for (int j = 0; j < 4; ++j) {
            int gcol = wn*64 + j*16 + quad*4;
            float4 bv = *(const float4*)(bias + gcol);
            float4 t;
            t.x = fmaxf(acc[i][j][0] + bv.x, 0.f); t.y = fmaxf(acc[i][j][1] + bv.y, 0.f);
            t.z = fmaxf(acc[i][j][2] + bv.z, 0.f); t.w = fmaxf(acc[i][j][3] + bv.w, 0.f);
            uint2 pu = make_uint2(pkpair(t.x, t.y), pkpair(t.z, t.w));
            *(uint2*)(out + (size_t)grow*128 + gcol) = pu;
        }
    }
}

// ---------------- conv2 (bf16 in) + fused relu + avg pool (operand-swapped) ----------
__global__ __launch_bounds__(256, 4) void conv2_pool(
    const bf16* __restrict__ X,     // [B][Tin][128]
    const bf16* __restrict__ wB,    // [128][640]
    const float* __restrict__ bias,
    float* __restrict__ outp,       // [B][128][64]
    int Tin, int Lout)
{
    __shared__ bf16 As[128][72];
    __shared__ bf16 Bs[128][72];
    int tid  = threadIdx.x;
    int lane = tid & 63;
    int wave = tid >> 6;
    int wm = wave >> 1, wn = wave & 1;
    int quad = lane >> 4, cl = lane & 15;
    int row0 = blockIdx.x * 128;
    int b  = row0 / Lout;
    int l0 = row0 % Lout;
    int d0 = l0 / 16;
    const bf16* Xb = X + (size_t)b*Tin*128;

    f32x4 acc[4][4] = {};

    for (int k0 = 0; k0 < 640; k0 += 64) {
        int tap = k0 / 128;
        int icb = k0 % 128;
        #pragma unroll
        for (int it = 0; it < 4; ++it) {
            int idx = it*256 + tid;
            int r = idx >> 3, kof = (idx & 7) * 8;
            int t = 2*(l0 + r) - 2 + tap;
            bf16x8 z = {0,0,0,0,0,0,0,0};
            if (t >= 0 && t < Tin) z = *(const bf16x8*)(Xb + (size_t)t*128 + icb + kof);
            *(bf16x8*)&As[r][kof] = z;
        }
        #pragma unroll
        for (int it = 0; it < 4; ++it) {
            int idx = it*256 + tid;
            int n = idx >> 3, kof = (idx & 7) * 8;
            *(bf16x8*)&Bs[n][kof] = *(const bf16x8*)(wB + (size_t)n*640 + k0 + kof);
        }
        __syncthreads();
        #pragma unroll
        for (int kk = 0; kk < 64; kk += 32) {
            bf16x8 af[4], bfr[4];
            #pragma unroll
            for (int i = 0; i < 4; ++i)
                af[i] = *(const bf16x8*)&As[wm*64 + i*16 + cl][kk + quad*8];
            #pragma unroll
            for (int j = 0; j < 4; ++j)
                bfr[j] = *(const bf16x8*)&Bs[wn*64 + j*16 + cl][kk + quad*8];
            #pragma unroll
            for (int i = 0; i < 4; ++i)
                #pragma unroll
                for (int j = 0; j < 4; ++j)
                    acc[i][j] = __builtin_amdgcn_mfma_f32_16x16x32_bf16(
                                    bfr[j], af[i], acc[i][j], 0, 0, 0);
        }
        __syncthreads();
    }

    #pragma unroll
    for (int j = 0; j < 4; ++j) {
        int gcol = wn*64 + j*16 + quad*4;
        float4 bv = *(const float4*)(bias + gcol);
        #pragma unroll
        for (int i = 0; i < 4; ++i) {
            float4 sp;
            sp.x = fmaxf(acc[i][j][0] + bv.x, 0.f);
            sp.y = fmaxf(acc[i][j][1] + bv.y, 0.f);
            sp.z = fmaxf(acc[i][j][2] + bv.z, 0.f);
            sp.w = fmaxf(acc[i][j][3] + bv.w, 0.f);
            #pragma unroll
            for (int off = 1; off <= 8; off <<= 1) {
                sp.x += __shfl_xor(sp.x, off);
                sp.y += __shfl_xor(sp.y, off);
                sp.z += __shfl_xor(sp.z, off);
                sp.w += __shfl_xor(sp.w, off);
            }
            if (cl == 0) {
                int d = d0 + wm*4 + i;
                float* op = outp + (size_t)b*8192 + (size_t)gcol*64 + d;
                op[0]   = sp.x * (1.f/16.f);
                op[64]  = sp.y * (1.f/16.f);
                op[128] = sp.z * (1.f/16.f);
                op[192] = sp.w * (1.f/16.f);
            }
        }
    }
}

extern "C" void kernel_launch(void* const* d_in, const int* in_sizes, int n_in,
                              void* d_out, int out_size, void* d_ws, size_t ws_size,
                              hipStream_t stream)
{
    (void)in_sizes; (void)n_in; (void)out_size; (void)ws_size;
    const float* x_in    = (const float*)d_in[0];
    const float* ln1_g   = (const float*)d_in[1];
    const float* ln1_b   = (const float*)d_in[2];
    const float* ln2_g   = (const float*)d_in[3];
    const float* ln2_b   = (const float*)d_in[4];
    const float* Lam_re  = (const float*)d_in[5];
    const float* Lam_im  = (const float*)d_in[6];
    const float* B_re    = (const float*)d_in[7];
    const float* B_im    = (const float*)d_in[8];
    const float* C_re    = (const float*)d_in[9];
    const float* C_im    = (const float*)d_in[10];
    const float* D_skip  = (const float*)d_in[11];
    const float* log_step= (const float*)d_in[12];
    const float* W1      = (const float*)d_in[13];
    const float* b1      = (const float*)d_in[14];
    const float* W2      = (const float*)d_in[15];
    const float* b2      = (const float*)d_in[16];
    const float* conv1_w = (const float*)d_in[17];
    const float* conv1_b = (const float*)d_in[18];
    const float* conv2_w = (const float*)d_in[19];
    const float* conv2_b = (const float*)d_in[20];
    float* out = (float*)d_out;

    // Workspace (~122 MB): Xbf bf16 32MB | Cbuf bf16 [BT,256] 64MB | Cv1 bf16 16MB
    //                      | munrs 1MB | params+carry+apow ~4MB
    char* ws = (char*)d_ws;
    bf16*   Xbf    = (bf16*) (ws);
    bf16*   Cbuf   = (bf16*) (ws + (size_t)33554432);
    bf16*   Cv1    = (bf16*) (ws + (size_t)100663296);
    float2* munrs  = (float2*)(ws + (size_t)117440512);
    char*   wreg   = ws + (size_t)118489088;
    bf16*   Wbu_bf = (bf16*)(wreg);                  // 131072
    bf16*   Wc_bf  = (bf16*)(wreg + 131072);         // 131072
    bf16*   W1_bf  = (bf16*)(wreg + 262144);         // 131072
    bf16*   W2_bf  = (bf16*)(wreg + 393216);         // 131072
    float*  Sb     = (float*)(wreg + 524288);        // 2048
    float*  biasb  = (float*)(wreg + 526336);        // 2048
    float*  S1     = (float*)(wreg + 528384);        // 2048
    float*  bias1p = (float*)(wreg + 530432);        // 2048
    float*  gd     = (float*)(wreg + 532480);        // 1024
    float*  bd     = (float*)(wreg + 533504);        // 1024
    float4* coefs  = (float4*)(wreg + 534528);       // 4096
    bf16*   wB1    = (bf16*)(wreg + 538624);         // 163840
    bf16*   wB2    = (bf16*)(wreg + 702464);         // 163840
    float2* carry  = (float2*)(wreg + 866304);       // 2 MB
    float2* apow   = (float2*)(wreg + 2963456);      // 2*64*128*8 = 131072

    prep_s5<<<2, 128, 0, stream>>>(Lam_re, Lam_im, B_re, B_im, C_re, C_im, log_step,
                                   ln1_g, ln1_b, D_skip,
                                   Wbu_bf, Wc_bf, Sb, biasb, gd, bd, coefs, apow);
    prep_w1<<<2, 256, 0, stream>>>(W1, b1, ln2_g, ln2_b, W1_bf, S1, bias1p);
    prep_w2<<<2, 128, 0, stream>>>(W2, W2_bf);
    prep_wB<<<640, 256, 0, stream>>>(conv1_w, conv2_w, wB1, wB2);

    for (int i = 0; i < 2; ++i) {
        // ---- LN1 + Wbu GEMM (Bu + munrs) ----
        if (i == 0)
            lngemm2<float><<<512, 512, 0, stream>>>(
                x_in, Wbu_bf, Sb, biasb, Cbuf, munrs);
        else
            lngemm2<bf16><<<512, 512, 0, stream>>>(
                Xbf, Wbu_bf + 32768, Sb + 256, biasb + 256, Cbuf, munrs);
        // ---- local scan + carry prefix ----
        scan_local<<<512, 256, 0, stream>>>((uint2*)Cbuf, coefs + i*NST, carry);
        scan_carry<<<16, 256, 0, stream>>>(carry, coefs + i*NST);
        // ---- fused: scan-fix + Wc GEMM + ud + resid + LN2 + W1 + gelu + W2 + resid ----
        if (i == 0)
            s5mlp<1><<<1024, 512, 0, stream>>>(
                Cbuf, x_in, Xbf, munrs, gd, bd, carry, apow,
                Wc_bf, W1_bf, W2_bf, S1, bias1p, b2);
        else
            s5mlp<0><<<1024, 512, 0, stream>>>(
                Cbuf, Xbf, Xbf, munrs, gd + 128, bd + 128, carry, apow + 64*128,
                Wc_bf + 32768, W1_bf + 32768, W2_bf + 32768,
                S1 + 256, bias1p + 256, b2 + 128);
    }

    // ---- head: conv1 (sigma-Xbf -> true Cv1) -> conv2+pool (-> d_out) ----
    conv1_mfma<<<512, 256, 0, stream>>>(Xbf, wB1, conv1_b, Cv1, 4096, 2048);
    conv2_pool<<<256, 256, 0, stream>>>(Cv1, wB2, conv2_b, out, 2048, 1024);
}

// Round 9
// 735.913 us; speedup vs baseline: 1.0748x; 1.0748x over previous
//
#include <hip/hip_runtime.h>
#include <math.h>

#define BATCH 32
#define TSEQ  4096
#define HD    128
#define NST   128
#define BT    (BATCH*TSEQ)     // 131072
#define LC    64               // scan chunk length
#define NCHK  (TSEQ/LC)        // 64 chunks

typedef unsigned short bf16;
typedef __attribute__((ext_vector_type(8))) short bf16x8;   // 8 bf16 = 4 VGPRs (MFMA A/B frag)
typedef __attribute__((ext_vector_type(4))) float f32x4;    // MFMA C/D frag

// sigma: storage index j -> true index h
//   sigma(j) = (j[6:5]<<5) | (j[3:2]<<3) | (j[4]<<2) | j[1:0]
//   inv(h): position j such that sigma(j)=h
__device__ __host__ inline int sig_f(int j) {
    return ((j >> 5) << 5) | (((j >> 2) & 3) << 3) | (((j >> 4) & 1) << 2) | (j & 3);
}
__device__ __host__ inline int inv_f(int h) {
    return ((h >> 5) << 5) | (((h >> 2) & 1) << 4) | (((h >> 3) & 3) << 2) | (h & 3);
}

__device__ inline float bf2f(bf16 s) {
    union { unsigned int u; float f; } v; v.u = ((unsigned int)s) << 16; return v.f;
}
__device__ inline bf16 f2bf(float f) {
    union { float f; unsigned int u; } v; v.f = f;
    unsigned int u = v.u;
    unsigned int r = (u + 0x7fffu + ((u >> 16) & 1u)) >> 16;
    return (bf16)r;
}
// pack two f32 -> bf16 pair (round-half-up) in ~3 VALU via v_perm
__device__ inline unsigned int pkpair(float lo, float hi) {
    union { float f; unsigned int u; } a, b;
    a.f = lo; b.f = hi;
    return __builtin_amdgcn_perm(b.u + 0x8000u, a.u + 0x8000u, 0x07060302u);
}
__device__ inline bf16x8 pack8f(float4 f0, float4 f1) {
    union { bf16x8 v; unsigned int u[4]; } t;
    t.u[0] = pkpair(f0.x, f0.y);
    t.u[1] = pkpair(f0.z, f0.w);
    t.u[2] = pkpair(f1.x, f1.y);
    t.u[3] = pkpair(f1.z, f1.w);
    return t.v;
}
__device__ inline float2 cmul2(float2 a, float2 b) {
    return make_float2(a.x*b.x - a.y*b.y, a.x*b.y + a.y*b.x);
}
// tanh-form gelu: max |diff vs exact erf-gelu| ~1e-3, under bf16 noise here
__device__ inline float gelu_f(float x) {
    float u = x*(0.7978845608f + 0.0356774081f*x*x);
    return __fdividef(x, 1.f + __expf(-2.f*u));
}
__device__ inline float2 upk(unsigned int w) {     // bf16 pair -> fp32 pair
    union { unsigned int u; float f; } a, b;
    a.u = w << 16; b.u = w & 0xffff0000u;
    return make_float2(a.f, b.f);
}
__device__ inline unsigned int pk(float2 x) { return pkpair(x.x, x.y); }

// ---------------- S5 param prep: g-folded W'bu, S/bias, Wc(sigma rows), ... ----------
// Xbf lives in SIGMA-column layout after layer-1 s5mlp. Hence:
//   - Wc rows sigma-permuted (storage row j holds true h=sigma(j)) -> s5mlp phase-A
//     output lands in hpx layout that directly feeds GEMM1.
//   - Wbu columns: true for i=0 (x_in is true-layout), sigma-permuted for i=1.
__global__ void prep_s5(const float* __restrict__ Lam_re, const float* __restrict__ Lam_im,
                        const float* __restrict__ B_re,  const float* __restrict__ B_im,
                        const float* __restrict__ C_re,  const float* __restrict__ C_im,
                        const float* __restrict__ log_step,
                        const float* __restrict__ ln1_g, const float* __restrict__ ln1_b,
                        const float* __restrict__ D_skip,
                        bf16* __restrict__ Wbu_bf,  // [2][256][128], row 2n=Re 2n+1=Im, g-folded
                        bf16* __restrict__ Wc_bf,   // [2][128][256], sigma rows
                        float* __restrict__ Sb, float* __restrict__ biasb,   // [2][256]
                        float* __restrict__ gd, float* __restrict__ bd,      // [2][128]
                        float4* __restrict__ coefs,
                        float2* __restrict__ apow)  // [2][64][128]: apow[i][j][n] = a^(j+1)
{
    int i = blockIdx.x, n = threadIdx.x;
    int in = i*NST + n;
    float lr = Lam_re[in], li = Lam_im[in];
    float dt = expf(log_step[in]);
    float ea = expf(lr*dt);
    float ar = ea*cosf(li*dt), ai = ea*sinf(li*dt);
    float xx = ar - 1.f, yy = ai;
    float den = lr*lr + li*li;
    float sr = (xx*lr + yy*li)/den;
    float si = (yy*lr - xx*li)/den;
    float2 a2 = make_float2(ar, ai);
    float2 p = a2;
    float2* apr = apow + (size_t)i*64*128;
    for (int j = 0; j < 64; ++j) {     // apow[j][n] = a^(j+1)
        apr[j*128 + n] = p;
        p = cmul2(p, a2);
    }
    // recompute a^64 via repeated squaring for exactness
    float2 q = a2;
    #pragma unroll
    for (int t = 0; t < 6; ++t) q = cmul2(q, q);
    coefs[in] = make_float4(ar, ai, q.x, q.y);

    const float* g  = ln1_g + i*HD;
    const float* bb = ln1_b + i*HD;
    const float* br = B_re + (size_t)in*HD;
    const float* bi = B_im + (size_t)in*HD;
    bf16* wb = Wbu_bf + (size_t)i*256*128;
    float s_re = 0.f, s_im = 0.f, bc_re = 0.f, bc_im = 0.f;
    for (int h = 0; h < HD; ++h) {
        float wre = sr*br[h] - si*bi[h];
        float wim = sr*bi[h] + si*br[h];
        bf16 wrb = f2bf(g[h]*wre), wib = f2bf(g[h]*wim);
        int hc = (i == 0) ? h : inv_f(h);   // i=1 consumes sigma-layout Xbf
        wb[(2*n)*128 + hc]   = wrb;
        wb[(2*n+1)*128 + hc] = wib;
        s_re += bf2f(wrb); s_im += bf2f(wib);
        bc_re += bb[h]*wre; bc_im += bb[h]*wim;
    }
    Sb[i*256 + 2*n] = s_re;     Sb[i*256 + 2*n+1] = s_im;
    biasb[i*256 + 2*n] = bc_re; biasb[i*256 + 2*n+1] = bc_im;

    const float* cr = C_re + (size_t)i*HD*NST;
    const float* ci = C_im + (size_t)i*HD*NST;
    bf16* wc = Wc_bf + (size_t)i*128*256;
    for (int h = 0; h < HD; ++h) {
        int jr = inv_f(h);                  // sigma rows
        wc[jr*256 + 2*n]   = f2bf( 2.f * cr[h*NST + n]);
        wc[jr*256 + 2*n+1] = f2bf(-2.f * ci[h*NST + n]);
    }
    gd[i*HD + n] = g[n]*D_skip[i*HD + n];
    bd[i*HD + n] = bb[n]*D_skip[i*HD + n];
}

// W1 -> g2-folded bf16, f-rows sigma-permuted (HW-verified R2-R8):
//   row j holds true f = sigma(j); GEMM1 D then packs directly into GEMM2 A-frags.
// K-columns (h) stay TRUE (double-sigma cancellation). S1/bias1p true-f-indexed.
__global__ void prep_w1(const float* __restrict__ W1, const float* __restrict__ b1,
                        const float* __restrict__ ln2_g, const float* __restrict__ ln2_b,
                        bf16* __restrict__ W1_bf, float* __restrict__ S1,
                        float* __restrict__ bias1p)
{
    int i = blockIdx.x, f = threadIdx.x;       // f in [0,256) true feature
    const float* g  = ln2_g + i*HD;
    const float* bb = ln2_b + i*HD;
    bf16* w = W1_bf + (size_t)i*256*128;
    int j = ((f >> 5) << 5) | (((f >> 2) & 1) << 4) | (((f >> 3) & 3) << 2) | (f & 3);
    float S = 0.f, bi_ = b1[i*256 + f];
    for (int h = 0; h < HD; ++h) {
        float wv = W1[(size_t)i*32768 + h*256 + f];
        bf16 wbv = f2bf(g[h]*wv);
        w[j*128 + h] = wbv;
        S += bf2f(wbv);
        bi_ += bb[h]*wv;
    }
    S1[i*256 + f] = S;
    bias1p[i*256 + f] = bi_;
}

// W2 -> bf16 transposed [h][f], h-rows SIGMA-permuted: storage row j holds true
// h=sigma(j). Phase-C output columns then align pairwise with hpx (residual in regs)
// and stores land at plain n0 positions of sigma-layout Xbf.
__global__ void prep_w2(const float* __restrict__ W2, bf16* __restrict__ W2_bf)
{
    int i = blockIdx.x, h = threadIdx.x;       // h in [0,128) true
    bf16* w = W2_bf + (size_t)i*128*256 + (size_t)inv_f(h)*256;
    for (int f = 0; f < 256; ++f)
        w[f] = f2bf(W2[(size_t)i*32768 + f*128 + h]);
}

// conv weights [c][ic][tap] -> bf16 [c][tap*128+icj]; conv1 consumes sigma-layout Xbf,
// so wB1 stores at position icj the weight of true channel sigma(icj). wB2 true.
__global__ void prep_wB(const float* __restrict__ w1, const float* __restrict__ w2,
                        bf16* __restrict__ wB1, bf16* __restrict__ wB2)
{
    int idx = blockIdx.x*256 + threadIdx.x;
    if (idx >= 163840) return;
    int r   = idx % 81920;
    int c   = r / 640;
    int tap = (r % 640) / 128;
    int icj = r % 128;
    if (idx < 81920) {
        wB1[r] = f2bf(w1[(c*128 + sig_f(icj))*5 + tap]);
    } else {
        wB2[r] = f2bf(w2[(c*128 + icj)*5 + tap]);
    }
}

// ---------------- fused LN + GEMM (K=128, N=256), bf16 out, 2 strips/wave ------------
// Operand-swapped MFMA: lane cl owns output row t directly. Stores per-row (mu,rs).
template<typename TA>
__global__ __launch_bounds__(512, 2) void lngemm2(
    const TA* __restrict__ A,          // [BT,128] fp32 (true) or bf16 (sigma; Wbu matches)
    const bf16* __restrict__ Bt,       // [256][128] g-folded
    const float* __restrict__ Svec, const float* __restrict__ bvec,  // [256]
    bf16* __restrict__ outB,           // [BT,256]
    float2* __restrict__ munrs)        // [BT]
{
    __shared__ bf16 Bs[256*136];       // 69632 B (+8 pad per row)
    __shared__ float Sl[256], bl[256];

    int tid = threadIdx.x;
    #pragma unroll
    for (int it = 0; it < 8; ++it) {
        int f = it*512 + tid;
        int n = f >> 4, kk = (f & 15)*8;
        *(bf16x8*)&Bs[n*136 + kk] = *(const bf16x8*)(Bt + n*128 + kk);
    }
    if (tid < 256) { Sl[tid] = Svec[tid]; bl[tid] = bvec[tid]; }
    __syncthreads();

    int wid = tid >> 6, lane = tid & 63;
    int quad = lane >> 4, cl = lane & 15;
    int s0 = blockIdx.x*16 + wid*2;
    size_t row0 = (size_t)s0*16 + cl;          // strip p -> row0 + p*16

    bf16x8 af[2][4];
    float mu[2], rs[2], mr[2];
    #pragma unroll
    for (int p = 0; p < 2; ++p) {
        size_t row = row0 + (size_t)p*16;
        float sm = 0.f, sq = 0.f;
        if constexpr (sizeof(TA) == 2) {
            const bf16* ar = (const bf16*)A + row*128;
            #pragma unroll
            for (int ks = 0; ks < 4; ++ks) {
                af[p][ks] = *(const bf16x8*)(ar + quad*8 + ks*32);
                union { bf16x8 v; unsigned int u[4]; } aa; aa.v = af[p][ks];
                #pragma unroll
                for (int jp = 0; jp < 4; ++jp) {
                    float2 vv = upk(aa.u[jp]);
                    sm += vv.x + vv.y;
                    sq += vv.x*vv.x + vv.y*vv.y;
                }
            }
        } else {
            const float* ar = (const float*)A + row*128;
            #pragma unroll
            for (int ks = 0; ks < 4; ++ks) {
                float4 f0 = *(const float4*)(ar + quad*8 + ks*32);
                float4 f1 = *(const float4*)(ar + quad*8 + ks*32 + 4);
                sm += f0.x + f0.y + f0.z + f0.w + f1.x + f1.y + f1.z + f1.w;
                sq += f0.x*f0.x + f0.y*f0.y + f0.z*f0.z + f0.w*f0.w
                    + f1.x*f1.x + f1.y*f1.y + f1.z*f1.z + f1.w*f1.w;
                af[p][ks] = pack8f(f0, f1);
            }
        }
        sm += __shfl_xor(sm, 16); sm += __shfl_xor(sm, 32);
        sq += __shfl_xor(sq, 16); sq += __shfl_xor(sq, 32);
        mu[p] = sm * (1.f/128.f);
        rs[p] = rsqrtf(sq*(1.f/128.f) - mu[p]*mu[p] + 1e-5f);
        mr[p] = mu[p]*rs[p];
        if (quad == 0) munrs[row] = make_float2(mu[p], rs[p]);
    }

    #pragma unroll
    for (int g = 0; g < 4; ++g) {
        f32x4 acc0[4] = {}, acc1[4] = {};
        #pragma unroll
        for (int t4 = 0; t4 < 4; ++t4) {
            const bf16* wrp = &Bs[(((g*4+t4)*16) + cl)*136 + quad*8];
            #pragma unroll
            for (int ks = 0; ks < 4; ++ks) {
                bf16x8 w = *(const bf16x8*)(wrp + ks*32);
                acc0[t4] = __builtin_amdgcn_mfma_f32_16x16x32_bf16(w, af[0][ks], acc0[t4], 0, 0, 0);
                acc1[t4] = __builtin_amdgcn_mfma_f32_16x16x32_bf16(w, af[1][ks], acc1[t4], 0, 0, 0);
            }
        }
        #pragma unroll
        for (int t4 = 0; t4 < 4; ++t4) {
            int n0 = (g*4+t4)*16 + quad*4;
            float4 S4 = *(const float4*)&Sl[n0];
            float4 b4 = *(const float4*)&bl[n0];
            float4 o;
            o.x = rs[0]*acc0[t4][0] - mr[0]*S4.x + b4.x;
            o.y = rs[0]*acc0[t4][1] - mr[0]*S4.y + b4.y;
            o.z = rs[0]*acc0[t4][2] - mr[0]*S4.z + b4.z;
            o.w = rs[0]*acc0[t4][3] - mr[0]*S4.w + b4.w;
            *(uint2*)(outB + row0*256 + n0) = make_uint2(pkpair(o.x, o.y), pkpair(o.z, o.w));
            o.x = rs[1]*acc1[t4][0] - mr[1]*S4.x + b4.x;
            o.y = rs[1]*acc1[t4][1] - mr[1]*S4.y + b4.y;
            o.z = rs[1]*acc1[t4][2] - mr[1]*S4.z + b4.z;
            o.w = rs[1]*acc1[t4][3] - mr[1]*S4.w + b4.w;
            *(uint2*)(outB + (row0+16)*256 + n0) = make_uint2(pkpair(o.x, o.y), pkpair(o.z, o.w));
        }
    }
}

// ---------------- fused S5-epilogue + MLP, single time-shared weight buffer ----------
// R8 post-mortem: time-shared 68KB buffer is correct (passed), but launch_bounds
// (512,4) capped the allocator at 64 VGPR -> spill (WRITE 364MB). Allocator-cap
// table (empirical): (512,2)->128, (512,4)->64, (1024,*)->64. At 128 VGPR the HW
// still fits 4 waves/SIMD (m69: occupancy halves at 64/128/256), so (512,2) gives
// BOTH the 128-reg budget R7 proved sufficient AND 2 blocks/CU (LDS 2x71=142KB<160).
// ONE 68KB buffer serves all 3 GEMMs: [128][264] (Wc/W2) == [256][132] (W1) = 67584B.
// Wc staged upfront; W1/W2 re-staged from global (L2-resident) via short-lived regs.
// hpx (phase-A bf16 out) == GEMM1 A-frags; hp1 == GEMM2 A-frags (sigma-construction);
// phase-C cols align with hpx for residual; stores at n0 => Xbf in sigma layout.
template<int FIRST>
__global__ __launch_bounds__(512, 2) void s5mlp(
    const bf16* __restrict__ A,        // [BT,256] Cbuf (post local scan)
    const void* resid,                 // [BT,128] fp32 true (FIRST) / bf16 sigma
    bf16* out,                         // [BT,128] sigma layout (may alias resid)
    const float2* __restrict__ munrs,
    const float* __restrict__ gdp, const float* __restrict__ bdp,   // true-h
    const float2* __restrict__ carry,  // [NCHK][B][128]
    const float2* __restrict__ apow,   // [64][128]
    const bf16* __restrict__ Wcp,      // [128][256] sigma rows
    const bf16* __restrict__ W1p,      // [256][128] sigma f-rows
    const bf16* __restrict__ W2p,      // [128][256] sigma h-rows
    const float* __restrict__ S1v, const float* __restrict__ b1v,   // [256] true-f
    const float* __restrict__ b2v)     // [128] true-h
{
    __shared__ bf16 Wl[128*264];       // 67584 B, time-shared: Wc -> W1 -> W2
    __shared__ float gdl[128], bdl[128], S1l[256], b1l[256], b2l[128];

    int tid = threadIdx.x;
    #pragma unroll
    for (int it = 0; it < 8; ++it) {   // Wc -> Wl as [128][264]
        int f = it*512 + tid;
        int n = f >> 5, kk = (f & 31)*8;
        *(bf16x8*)&Wl[n*264 + kk] = *(const bf16x8*)(Wcp + n*256 + kk);
    }
    if (tid < 128)      { gdl[tid] = gdp[tid]; bdl[tid] = bdp[tid]; }
    else if (tid < 384) { S1l[tid-128] = S1v[tid-128]; b1l[tid-128] = b1v[tid-128]; }
    else                { b2l[tid-384] = b2v[tid-384]; }
    __syncthreads();

    int wid = tid >> 6, lane = tid & 63;
    int quad = lane >> 4, cl = lane & 15;
    int s = blockIdx.x*8 + wid;
    size_t row = (size_t)s*16 + cl;

    float2 m2 = munrs[row];
    float mu = m2.x, rs = m2.y;

    // A-frags from Cbuf + fused cross-chunk scan fix
    bf16x8 af[8];
    {
        const bf16* ar = A + row*256 + quad*8;
        int b  = (int)(row >> 12);
        int tp = (int)(row & 4095);
        int cc = tp >> 6, j = tp & 63;
        const float2* cin = carry + (size_t)cc*(BATCH*NST) + (size_t)b*NST;
        const float2* ap  = apow + (size_t)j*128;
        #pragma unroll
        for (int ks = 0; ks < 8; ++ks) {
            union { bf16x8 v; unsigned int u[4]; } t;
            t.v = *(const bf16x8*)(ar + ks*32);
            int n0c = quad*4 + ks*16;
            #pragma unroll
            for (int jp = 0; jp < 4; ++jp) {
                float2 v  = upk(t.u[jp]);
                float2 ad = cmul2(ap[n0c+jp], cin[n0c+jp]);
                t.u[jp] = pk(make_float2(v.x + ad.x, v.y + ad.y));
            }
            af[ks] = t.v;
        }
    }

    // ---- phase A: Wc GEMM (sigma rows); per-nt acc retired immediately ----
    union { unsigned int u[8][2]; bf16x8 v[4]; } hpx;
    #pragma unroll
    for (int nt = 0; nt < 8; ++nt) {
        const bf16* wrp = &Wl[(nt*16 + cl)*264 + quad*8];
        f32x4 a0 = {};
        #pragma unroll
        for (int ks = 0; ks < 8; ++ks)
            a0 = __builtin_amdgcn_mfma_f32_16x16x32_bf16(
                     *(const bf16x8*)(wrp + ks*32), af[ks], a0, 0, 0, 0);
        int fb = ((nt >> 1) << 5) + (quad << 3) + ((nt & 1) << 2);  // true-h base
        float4 rv;
        if constexpr (FIRST) {
            rv = *(const float4*)((const float*)resid + row*128 + fb);
        } else {
            int n0 = nt*16 + quad*4;          // sigma-layout position
            ushort4 u4 = *(const ushort4*)((const bf16*)resid + row*128 + n0);
            rv = make_float4(bf2f(u4.x), bf2f(u4.y), bf2f(u4.z), bf2f(u4.w));
        }
        float4 g4 = *(const float4*)&gdl[fb];
        float4 b4 = *(const float4*)&bdl[fb];
        float4 o;
        o.x = rv.x + a0[0] + (rv.x - mu)*rs*g4.x + b4.x;
        o.y = rv.y + a0[1] + (rv.y - mu)*rs*g4.y + b4.y;
        o.z = rv.z + a0[2] + (rv.z - mu)*rs*g4.z + b4.z;
        o.w = rv.w + a0[3] + (rv.w - mu)*rs*g4.w + b4.w;
        hpx.u[nt][0] = pkpair(o.x, o.y);
        hpx.u[nt][1] = pkpair(o.z, o.w);
    }

    __syncthreads();                   // all waves done reading Wc

    // ---- stage W1 -> regs (LN2 stats overlap the load latency) -> Wl [256][132] ----
    bf16x8 w1r[8];
    #pragma unroll
    for (int it = 0; it < 8; ++it) {
        int f = it*512 + tid;
        w1r[it] = *(const bf16x8*)(W1p + (size_t)(f >> 4)*128 + (f & 15)*8);
    }

    // LN2 stats on hpx (VALU + shfl; overlaps W1 load latency)
    float sm = 0.f, sq = 0.f;
    #pragma unroll
    for (int nt = 0; nt < 8; ++nt)
        #pragma unroll
        for (int e = 0; e < 2; ++e) {
            float2 vv = upk(hpx.u[nt][e]);
            sm += vv.x + vv.y;
            sq += vv.x*vv.x + vv.y*vv.y;
        }
    sm += __shfl_xor(sm, 16); sm += __shfl_xor(sm, 32);
    sq += __shfl_xor(sq, 16); sq += __shfl_xor(sq, 32);
    float mu2 = sm * (1.f/128.f);
    float rs2 = rsqrtf(sq*(1.f/128.f) - mu2*mu2 + 1e-5f);
    float mr2 = mu2*rs2;

    #pragma unroll
    for (int it = 0; it < 8; ++it) {
        int f = it*512 + tid;
        *(bf16x8*)&Wl[(f >> 4)*132 + (f & 15)*8] = w1r[it];
    }
    __syncthreads();                   // W1 visible

    // ---- issue W2 loads (held through phase B; latency hidden under MFMAs) ----
    bf16x8 w2r[8];
    #pragma unroll
    for (int it = 0; it < 8; ++it) {
        int f = it*512 + tid;
        w2r[it] = *(const bf16x8*)(W2p + (size_t)(f >> 5)*256 + (f & 31)*8);
    }

    // ---- phase B: W1 GEMM + gelu -> hp1 (reads Wl as [256][132]) ----
    union { unsigned int u[16][2]; bf16x8 v[8]; } hp1;
    #pragma unroll
    for (int half = 0; half < 2; ++half) {
        #pragma unroll
        for (int nt = 0; nt < 8; ++nt) {
            int NT = half*8 + nt;
            const bf16* wrp = &Wl[((NT*16) + cl)*132 + quad*8];
            f32x4 a0 = {};
            #pragma unroll
            for (int ks = 0; ks < 4; ++ks)
                a0 = __builtin_amdgcn_mfma_f32_16x16x32_bf16(
                         *(const bf16x8*)(wrp + ks*32), hpx.v[ks], a0, 0, 0, 0);
            int fb = ((NT >> 1) << 5) + (quad << 3) + ((NT & 1) << 2);  // true-f base
            float4 S4 = *(const float4*)&S1l[fb];
            float4 b4 = *(const float4*)&b1l[fb];
            float4 o;
            o.x = gelu_f(rs2*a0[0] - mr2*S4.x + b4.x);
            o.y = gelu_f(rs2*a0[1] - mr2*S4.y + b4.y);
            o.z = gelu_f(rs2*a0[2] - mr2*S4.z + b4.z);
            o.w = gelu_f(rs2*a0[3] - mr2*S4.w + b4.w);
            hp1.u[NT][0] = pkpair(o.x, o.y);
            hp1.u[NT][1] = pkpair(o.z, o.w);
        }
    }

    __syncthreads();                   // all waves done reading W1
    #pragma unroll
    for (int it = 0; it < 8; ++it) {   // W2 regs -> Wl as [128][264]
        int f = it*512 + tid;
        *(bf16x8*)&Wl[(f >> 5)*264 + (f & 31)*8] = w2r[it];
    }
    __syncthreads();                   // W2 visible

    // ---- phase C: W2 GEMM (sigma rows); + b2 + resid(hpx) -> store (sigma layout) ---
    #pragma unroll
    for (int nt = 0; nt < 8; ++nt) {
        const bf16* wrp = &Wl[(nt*16 + cl)*264 + quad*8];
        f32x4 a0 = {};
        #pragma unroll
        for (int ks = 0; ks < 8; ++ks)
            a0 = __builtin_amdgcn_mfma_f32_16x16x32_bf16(
                     *(const bf16x8*)(wrp + ks*32), hp1.v[ks], a0, 0, 0, 0);
        int fb = ((nt >> 1) << 5) + (quad << 3) + ((nt & 1) << 2);  // true-h base
        int n0 = nt*16 + quad*4;                                    // sigma position
        float4 b4 = *(const float4*)&b2l[fb];
        float2 r01 = upk(hpx.u[nt][0]);
        float2 r23 = upk(hpx.u[nt][1]);
        float4 o;
        o.x = a0[0] + b4.x + r01.x;
        o.y = a0[1] + b4.y + r01.y;
        o.z = a0[2] + b4.z + r23.x;
        o.w = a0[3] + b4.w + r23.y;
        *(uint2*)(out + row*128 + n0) = make_uint2(pkpair(o.x, o.y), pkpair(o.z, o.w));
    }
}

// ---------------- chunked scan on bf16-pair xs: x_t = a*x_{t-1} + Bu_t ---------------
// Local pass only; cross-chunk fix is fused into s5mlp. 2 states/thread (uint2, 8B/lane;
// R3 best-total config).
__global__ __launch_bounds__(256) void scan_local(uint2* __restrict__ xs,
                                                  const float4* __restrict__ coefs,
                                                  float2* __restrict__ carry)
{
    int flat = blockIdx.x*256 + threadIdx.x;  // 2^17
    int n2 = flat & 63;                        // handles states 2*n2, 2*n2+1
    int b = (flat >> 6) & 31;
    int c = flat >> 11;
    float4 cf0 = coefs[2*n2], cf1 = coefs[2*n2+1];
    float2 a0 = make_float2(cf0.x, cf0.y);
    float2 a1 = make_float2(cf1.x, cf1.y);
    uint2* base = xs + ((size_t)(b*TSEQ + c*LC))*64 + n2;
    float2 x0 = make_float2(0.f, 0.f), x1 = make_float2(0.f, 0.f);
    for (int j = 0; j < LC; ++j) {
        uint2 v = base[(size_t)j*64];
        float2 v0 = upk(v.x), v1 = upk(v.y);
        x0 = make_float2(a0.x*x0.x - a0.y*x0.y + v0.x, a0.x*x0.y + a0.y*x0.x + v0.y);
        x1 = make_float2(a1.x*x1.x - a1.y*x1.y + v1.x, a1.x*x1.y + a1.y*x1.x + v1.y);
        base[(size_t)j*64] = make_uint2(pk(x0), pk(x1));
    }
    carry[c*(BATCH*NST) + b*NST + 2*n2]   = x0;
    carry[c*(BATCH*NST) + b*NST + 2*n2+1] = x1;
}

__global__ void scan_carry(float2* __restrict__ carry, const float4* __restrict__ coefs)
{
    int flat = blockIdx.x*256 + threadIdx.x;  // 4096 = B*N
    int n = flat & 127;
    float4 cf = coefs[n];
    float2 aL = make_float2(cf.z, cf.w);
    float2 x = make_float2(0.f, 0.f);
    for (int c = 0; c < NCHK; ++c) {
        float2* p = carry + c*(BATCH*NST) + flat;
        float2 v = *p;
        *p = x;                                // exclusive prefix
        x = make_float2(aL.x*x.x - aL.y*x.y + v.x, aL.x*x.y + aL.y*x.x + v.y);
    }
}

// ---------------- conv1: bf16 in (sigma channels; weights pre-permuted), MFMA --------
__global__ __launch_bounds__(256, 4) void conv1_mfma(
    const bf16* __restrict__ X,
    const bf16* __restrict__ wB,    // [128][640]
    const float* __restrict__ bias,
    bf16* __restrict__ out,         // [B*Lout][128]
    int Tin, int Lout)
{
    __shared__ bf16 As[128][72];
    __shared__ bf16 Bs[128][72];
    int tid  = threadIdx.x;
    int lane = tid & 63;
    int wave = tid >> 6;
    int wm = wave >> 1, wn = wave & 1;
    int quad = lane >> 4, cl = lane & 15;
    int row0 = blockIdx.x * 128;
    int b  = row0 / Lout;
    int l0 = row0 % Lout;
    const bf16* Xb = X + (size_t)b*Tin*128;

    f32x4 acc[4][4] = {};

    for (int k0 = 0; k0 < 640; k0 += 64) {
        int tap = k0 / 128;
        int icb = k0 % 128;
        #pragma unroll
        for (int it = 0; it < 4; ++it) {
            int idx = it*256 + tid;
            int r = idx >> 3, kof = (idx & 7) * 8;
            int t = 2*(l0 + r) - 2 + tap;
            bf16x8 z = {0,0,0,0,0,0,0,0};
            if (t >= 0 && t < Tin) z = *(const bf16x8*)(Xb + (size_t)t*128 + icb + kof);
            *(bf16x8*)&As[r][kof] = z;
        }
        #pragma unroll
        for (int it = 0; it < 4; ++it) {
            int idx = it*256 + tid;
            int n = idx >> 3, kof = (idx & 7) * 8;
            *(bf16x8*)&Bs[n][kof] = *(const bf16x8*)(wB + (size_t)n*640 + k0 + kof);
        }
        __syncthreads();
        #pragma unroll
        for (int kk = 0; kk < 64; kk += 32) {
            bf16x8 af[4], bfr[4];
            #pragma unroll
            for (int i = 0; i < 4; ++i)
                af[i] = *(const bf16x8*)&As[wm*64 + i*16 + cl][kk + quad*8];
            #pragma unroll
            for (int j = 0; j < 4; ++j)
                bfr[j] = *(const bf16x8*)&Bs[wn*64 + j*16 + cl][kk + quad*8];
            #pragma unroll
            for (int i = 0; i < 4; ++i)
                #pragma unroll
                for (int j = 0; j < 4; ++j)
                    acc[i][j] = __builtin_amdgcn_mfma_f32_16x16x32_bf16(
                                    bfr[j], af[i], acc[i][j], 0, 0, 0);
        }
        __syncthreads();
    }

    #pragma unroll
    for (int i = 0; i < 4; ++i) {
        int grow = row0 + wm*64 + i*16 + cl;
        #pragma unroll
        for (int j = 0; j < 4; ++j) {
            int gcol = wn*64 + j*16 + quad*4;
            float4 bv = *(const float4*)(bias + gcol);
            float4 t;
            t.x = fmaxf(acc[i][j][0] + bv.x, 0.f); t.y = fmaxf(acc[i][j][1] + bv.y, 0.f);
            t.z = fmaxf(acc[i][j][2] + bv.z, 0.f); t.w = fmaxf(acc[i][j][3] + bv.w, 0.f);
            uint2 pu = make_uint2(pkpair(t.x, t.y), pkpair(t.z, t.w));
            *(uint2*)(out + (size_t)grow*128 + gcol) = pu;
        }
    }
}

// ---------------- conv2 (bf16 in) + fused relu + avg pool (operand-swapped) ----------
__global__ __launch_bounds__(256, 4) void conv2_pool(
    const bf16* __restrict__ X,     // [B][Tin][128]
    const bf16* __restrict__ wB,    // [128][640]
    const float* __restrict__ bias,
    float* __restrict__ outp,       // [B][128][64]
    int Tin, int Lout)
{
    __shared__ bf16 As[128][72];
    __shared__ bf16 Bs[128][72];
    int tid  = threadIdx.x;
    int lane = tid & 63;
    int wave = tid >> 6;
    int wm = wave >> 1, wn = wave & 1;
    int quad = lane >> 4, cl = lane & 15;
    int row0 = blockIdx.x * 128;
    int b  = row0 / Lout;
    int l0 = row0 % Lout;
    int d0 = l0 / 16;
    const bf16* Xb = X + (size_t)b*Tin*128;

    f32x4 acc[4][4] = {};

    for (int k0 = 0; k0 < 640; k0 += 64) {
        int tap = k0 / 128;
        int icb = k0 % 128;
        #pragma unroll
        for (int it = 0; it < 4; ++it) {
            int idx = it*256 + tid;
            int r = idx >> 3, kof = (idx & 7) * 8;
            int t = 2*(l0 + r) - 2 + tap;
            bf16x8 z = {0,0,0,0,0,0,0,0};
            if (t >= 0 && t < Tin) z = *(const bf16x8*)(Xb + (size_t)t*128 + icb + kof);
            *(bf16x8*)&As[r][kof] = z;
        }
        #pragma unroll
        for (int it = 0; it < 4; ++it) {
            int idx = it*256 + tid;
            int n = idx >> 3, kof = (idx & 7) * 8;
            *(bf16x8*)&Bs[n][kof] = *(const bf16x8*)(wB + (size_t)n*640 + k0 + kof);
        }
        __syncthreads();
        #pragma unroll
        for (int kk = 0; kk < 64; kk += 32) {
            bf16x8 af[4], bfr[4];
            #pragma unroll
            for (int i = 0; i < 4; ++i)
                af[i] = *(const bf16x8*)&As[wm*64 + i*16 + cl][kk + quad*8];
            #pragma unroll
            for (int j = 0; j < 4; ++j)
                bfr[j] = *(const bf16x8*)&Bs[wn*64 + j*16 + cl][kk + quad*8];
            #pragma unroll
            for (int i = 0; i < 4; ++i)
                #pragma unroll
                for (int j = 0; j < 4; ++j)
                    acc[i][j] = __builtin_amdgcn_mfma_f32_16x16x32_bf16(
                                    bfr[j], af[i], acc[i][j], 0, 0, 0);
        }
        __syncthreads();
    }

    #pragma unroll
    for (int j = 0; j < 4; ++j) {
        int gcol = wn*64 + j*16 + quad*4;
        float4 bv = *(const float4*)(bias + gcol);
        #pragma unroll
        for (int i = 0; i < 4; ++i) {
            float4 sp;
            sp.x = fmaxf(acc[i][j][0] + bv.x, 0.f);
            sp.y = fmaxf(acc[i][j][1] + bv.y, 0.f);
            sp.z = fmaxf(acc[i][j][2] + bv.z, 0.f);
            sp.w = fmaxf(acc[i][j][3] + bv.w, 0.f);
            #pragma unroll
            for (int off = 1; off <= 8; off <<= 1) {
                sp.x += __shfl_xor(sp.x, off);
                sp.y += __shfl_xor(sp.y, off);
                sp.z += __shfl_xor(sp.z, off);
                sp.w += __shfl_xor(sp.w, off);
            }
            if (cl == 0) {
                int d = d0 + wm*4 + i;
                float* op = outp + (size_t)b*8192 + (size_t)gcol*64 + d;
                op[0]   = sp.x * (1.f/16.f);
                op[64]  = sp.y * (1.f/16.f);
                op[128] = sp.z * (1.f/16.f);
                op[192] = sp.w * (1.f/16.f);
            }
        }
    }
}

extern "C" void kernel_launch(void* const* d_in, const int* in_sizes, int n_in,
                              void* d_out, int out_size, void* d_ws, size_t ws_size,
                              hipStream_t stream)
{
    (void)in_sizes; (void)n_in; (void)out_size; (void)ws_size;
    const float* x_in    = (const float*)d_in[0];
    const float* ln1_g   = (const float*)d_in[1];
    const float* ln1_b   = (const float*)d_in[2];
    const float* ln2_g   = (const float*)d_in[3];
    const float* ln2_b   = (const float*)d_in[4];
    const float* Lam_re  = (const float*)d_in[5];
    const float* Lam_im  = (const float*)d_in[6];
    const float* B_re    = (const float*)d_in[7];
    const float* B_im    = (const float*)d_in[8];
    const float* C_re    = (const float*)d_in[9];
    const float* C_im    = (const float*)d_in[10];
    const float* D_skip  = (const float*)d_in[11];
    const float* log_step= (const float*)d_in[12];
    const float* W1      = (const float*)d_in[13];
    const float* b1      = (const float*)d_in[14];
    const float* W2      = (const float*)d_in[15];
    const float* b2      = (const float*)d_in[16];
    const float* conv1_w = (const float*)d_in[17];
    const float* conv1_b = (const float*)d_in[18];
    const float* conv2_w = (const float*)d_in[19];
    const float* conv2_b = (const float*)d_in[20];
    float* out = (float*)d_out;

    // Workspace (~122 MB): Xbf bf16 32MB | Cbuf bf16 [BT,256] 64MB | Cv1 bf16 16MB
    //                      | munrs 1MB | params+carry+apow ~4MB
    char* ws = (char*)d_ws;
    bf16*   Xbf    = (bf16*) (ws);
    bf16*   Cbuf   = (bf16*) (ws + (size_t)33554432);
    bf16*   Cv1    = (bf16*) (ws + (size_t)100663296);
    float2* munrs  = (float2*)(ws + (size_t)117440512);
    char*   wreg   = ws + (size_t)118489088;
    bf16*   Wbu_bf = (bf16*)(wreg);                  // 131072
    bf16*   Wc_bf  = (bf16*)(wreg + 131072);         // 131072
    bf16*   W1_bf  = (bf16*)(wreg + 262144);         // 131072
    bf16*   W2_bf  = (bf16*)(wreg + 393216);         // 131072
    float*  Sb     = (float*)(wreg + 524288);        // 2048
    float*  biasb  = (float*)(wreg + 526336);        // 2048
    float*  S1     = (float*)(wreg + 528384);        // 2048
    float*  bias1p = (float*)(wreg + 530432);        // 2048
    float*  gd     = (float*)(wreg + 532480);        // 1024
    float*  bd     = (float*)(wreg + 533504);        // 1024
    float4* coefs  = (float4*)(wreg + 534528);       // 4096
    bf16*   wB1    = (bf16*)(wreg + 538624);         // 163840
    bf16*   wB2    = (bf16*)(wreg + 702464);         // 163840
    float2* carry  = (float2*)(wreg + 866304);       // 2 MB
    float2* apow   = (float2*)(wreg + 2963456);      // 2*64*128*8 = 131072

    prep_s5<<<2, 128, 0, stream>>>(Lam_re, Lam_im, B_re, B_im, C_re, C_im, log_step,
                                   ln1_g, ln1_b, D_skip,
                                   Wbu_bf, Wc_bf, Sb, biasb, gd, bd, coefs, apow);
    prep_w1<<<2, 256, 0, stream>>>(W1, b1, ln2_g, ln2_b, W1_bf, S1, bias1p);
    prep_w2<<<2, 128, 0, stream>>>(W2, W2_bf);
    prep_wB<<<640, 256, 0, stream>>>(conv1_w, conv2_w, wB1, wB2);

    for (int i = 0; i < 2; ++i) {
        // ---- LN1 + Wbu GEMM (Bu + munrs) ----
        if (i == 0)
            lngemm2<float><<<512, 512, 0, stream>>>(
                x_in, Wbu_bf, Sb, biasb, Cbuf, munrs);
        else
            lngemm2<bf16><<<512, 512, 0, stream>>>(
                Xbf, Wbu_bf + 32768, Sb + 256, biasb + 256, Cbuf, munrs);
        // ---- local scan + carry prefix ----
        scan_local<<<512, 256, 0, stream>>>((uint2*)Cbuf, coefs + i*NST, carry);
        scan_carry<<<16, 256, 0, stream>>>(carry, coefs + i*NST);
        // ---- fused: scan-fix + Wc GEMM + ud + resid + LN2 + W1 + gelu + W2 + resid ----
        if (i == 0)
            s5mlp<1><<<1024, 512, 0, stream>>>(
                Cbuf, x_in, Xbf, munrs, gd, bd, carry, apow,
                Wc_bf, W1_bf, W2_bf, S1, bias1p, b2);
        else
            s5mlp<0><<<1024, 512, 0, stream>>>(
                Cbuf, Xbf, Xbf, munrs, gd + 128, bd + 128, carry, apow + 64*128,
                Wc_bf + 32768, W1_bf + 32768, W2_bf + 32768,
                S1 + 256, bias1p + 256, b2 + 128);
    }

    // ---- head: conv1 (sigma-Xbf -> true Cv1) -> conv2+pool (-> d_out) ----
    conv1_mfma<<<512, 256, 0, stream>>>(Xbf, wB1, conv1_b, Cv1, 4096, 2048);
    conv2_pool<<<256, 256, 0, stream>>>(Cv1, wB2, conv2_b, out, 2048, 1024);
}

// Round 10
// 517.677 us; speedup vs baseline: 1.5279x; 1.4216x over previous
//
#include <hip/hip_runtime.h>
#include <math.h>

#define BATCH 32
#define TSEQ  4096
#define HD    128
#define NST   128
#define BT    (BATCH*TSEQ)     // 131072
#define LC    64               // scan chunk length
#define NCHK  (TSEQ/LC)        // 64 chunks

typedef unsigned short bf16;
typedef __attribute__((ext_vector_type(8))) short bf16x8;   // 8 bf16 = 4 VGPRs (MFMA A/B frag)
typedef __attribute__((ext_vector_type(4))) float f32x4;    // MFMA C/D frag

__device__ inline float bf2f(bf16 s) {
    union { unsigned int u; float f; } v; v.u = ((unsigned int)s) << 16; return v.f;
}
__device__ inline bf16 f2bf(float f) {
    union { float f; unsigned int u; } v; v.f = f;
    unsigned int u = v.u;
    unsigned int r = (u + 0x7fffu + ((u >> 16) & 1u)) >> 16;
    return (bf16)r;
}
// pack two f32 -> bf16 pair (round-half-up) in ~3 VALU via v_perm
__device__ inline unsigned int pkpair(float lo, float hi) {
    union { float f; unsigned int u; } a, b;
    a.f = lo; b.f = hi;
    return __builtin_amdgcn_perm(b.u + 0x8000u, a.u + 0x8000u, 0x07060302u);
}
__device__ inline bf16x8 pack8f(float4 f0, float4 f1) {
    union { bf16x8 v; unsigned int u[4]; } t;
    t.u[0] = pkpair(f0.x, f0.y);
    t.u[1] = pkpair(f0.z, f0.w);
    t.u[2] = pkpair(f1.x, f1.y);
    t.u[3] = pkpair(f1.z, f1.w);
    return t.v;
}
__device__ inline float2 cmul2(float2 a, float2 b) {
    return make_float2(a.x*b.x - a.y*b.y, a.x*b.y + a.y*b.x);
}
// tanh-form gelu: max |diff vs exact erf-gelu| ~1e-3, under bf16 noise here
__device__ inline float gelu_f(float x) {
    float u = x*(0.7978845608f + 0.0356774081f*x*x);
    return __fdividef(x, 1.f + __expf(-2.f*u));
}
__device__ inline float2 upk(unsigned int w) {     // bf16 pair -> fp32 pair
    union { unsigned int u; float f; } a, b;
    a.u = w << 16; b.u = w & 0xffff0000u;
    return make_float2(a.f, b.f);
}
__device__ inline unsigned int pk(float2 x) { return pkpair(x.x, x.y); }

// ---------------- S5 param prep: g-folded W'bu, S/bias, Wc, gd/bd, coefs, apow -------
__global__ void prep_s5(const float* __restrict__ Lam_re, const float* __restrict__ Lam_im,
                        const float* __restrict__ B_re,  const float* __restrict__ B_im,
                        const float* __restrict__ C_re,  const float* __restrict__ C_im,
                        const float* __restrict__ log_step,
                        const float* __restrict__ ln1_g, const float* __restrict__ ln1_b,
                        const float* __restrict__ D_skip,
                        bf16* __restrict__ Wbu_bf,  // [2][256][128], row 2n=Re 2n+1=Im, g-folded
                        bf16* __restrict__ Wc_bf,   // [2][128][256], col 2n=2Cre 2n+1=-2Cim
                        float* __restrict__ Sb, float* __restrict__ biasb,   // [2][256]
                        float* __restrict__ gd, float* __restrict__ bd,      // [2][128]
                        float4* __restrict__ coefs,
                        float2* __restrict__ apow)  // [2][64][128]: apow[i][j][n] = a^(j+1)
{
    int i = blockIdx.x, n = threadIdx.x;
    int in = i*NST + n;
    float lr = Lam_re[in], li = Lam_im[in];
    float dt = expf(log_step[in]);
    float ea = expf(lr*dt);
    float ar = ea*cosf(li*dt), ai = ea*sinf(li*dt);
    float xx = ar - 1.f, yy = ai;
    float den = lr*lr + li*li;
    float sr = (xx*lr + yy*li)/den;
    float si = (yy*lr - xx*li)/den;
    float2 a2 = make_float2(ar, ai);
    float2 p = a2;
    float2* apr = apow + (size_t)i*64*128;
    for (int j = 0; j < 64; ++j) {     // apow[j][n] = a^(j+1)
        apr[j*128 + n] = p;
        p = cmul2(p, a2);
    }
    // recompute a^64 via repeated squaring for exactness
    float2 q = a2;
    #pragma unroll
    for (int t = 0; t < 6; ++t) q = cmul2(q, q);
    coefs[in] = make_float4(ar, ai, q.x, q.y);

    const float* g  = ln1_g + i*HD;
    const float* bb = ln1_b + i*HD;
    const float* br = B_re + (size_t)in*HD;
    const float* bi = B_im + (size_t)in*HD;
    bf16* wb = Wbu_bf + (size_t)i*256*128;
    float s_re = 0.f, s_im = 0.f, bc_re = 0.f, bc_im = 0.f;
    for (int h = 0; h < HD; ++h) {
        float wre = sr*br[h] - si*bi[h];
        float wim = sr*bi[h] + si*br[h];
        bf16 wrb = f2bf(g[h]*wre), wib = f2bf(g[h]*wim);
        wb[(2*n)*128 + h]   = wrb;
        wb[(2*n+1)*128 + h] = wib;
        s_re += bf2f(wrb); s_im += bf2f(wib);
        bc_re += bb[h]*wre; bc_im += bb[h]*wim;
    }
    Sb[i*256 + 2*n] = s_re;     Sb[i*256 + 2*n+1] = s_im;
    biasb[i*256 + 2*n] = bc_re; biasb[i*256 + 2*n+1] = bc_im;

    const float* cr = C_re + (size_t)i*HD*NST;
    const float* ci = C_im + (size_t)i*HD*NST;
    bf16* wc = Wc_bf + (size_t)i*128*256;
    for (int h = 0; h < HD; ++h) {
        wc[h*256 + 2*n]   = f2bf( 2.f * cr[h*NST + n]);
        wc[h*256 + 2*n+1] = f2bf(-2.f * ci[h*NST + n]);
    }
    gd[i*HD + n] = g[n]*D_skip[i*HD + n];
    bd[i*HD + n] = bb[n]*D_skip[i*HD + n];
}

// W1 -> g2-folded bf16, stored at PERMUTED row j so that fused-MLP GEMM1's D layout
// is directly consumable as GEMM2's B operand (kills the cross-quad shfl bridge):
//   sigma(16*NT + 4*q + r) = 32*(NT>>1) + 8*q + 4*(NT&1) + r  (true feature f)
//   inverse: j = 32*(f>>5) + 16*((f>>2)&1) + 4*((f>>3)&3) + (f&3)
// S1/bias1p stay true-f-indexed. (HW-verified R2-R9.)
__global__ void prep_w1(const float* __restrict__ W1, const float* __restrict__ b1,
                        const float* __restrict__ ln2_g, const float* __restrict__ ln2_b,
                        bf16* __restrict__ W1_bf, float* __restrict__ S1,
                        float* __restrict__ bias1p)
{
    int i = blockIdx.x, f = threadIdx.x;       // f in [0,256) true feature
    const float* g  = ln2_g + i*HD;
    const float* bb = ln2_b + i*HD;
    bf16* w = W1_bf + (size_t)i*256*128;
    int j = ((f >> 5) << 5) | (((f >> 2) & 1) << 4) | (((f >> 3) & 3) << 2) | (f & 3);
    float S = 0.f, bi_ = b1[i*256 + f];
    for (int h = 0; h < HD; ++h) {
        float wv = W1[(size_t)i*32768 + h*256 + f];
        bf16 wbv = f2bf(g[h]*wv);
        w[j*128 + h] = wbv;
        S += bf2f(wbv);
        bi_ += bb[h]*wv;
    }
    S1[i*256 + f] = S;
    bias1p[i*256 + f] = bi_;
}

// W2 -> plain bf16 transposed [h][f]
__global__ void prep_w2(const float* __restrict__ W2, bf16* __restrict__ W2_bf)
{
    int i = blockIdx.x, h = threadIdx.x;       // h in [0,128)
    bf16* w = W2_bf + (size_t)i*128*256;
    for (int f = 0; f < 256; ++f)
        w[h*256 + f] = f2bf(W2[(size_t)i*32768 + f*128 + h]);
}

// conv weights [c][ic][tap] -> bf16 [c][tap*128+ic]
__global__ void prep_wB(const float* __restrict__ w1, const float* __restrict__ w2,
                        bf16* __restrict__ wB1, bf16* __restrict__ wB2)
{
    int idx = blockIdx.x*256 + threadIdx.x;
    if (idx >= 163840) return;
    const float* w = (idx < 81920) ? w1 : w2;
    bf16* wb       = (idx < 81920) ? wB1 : wB2;
    int r   = idx % 81920;
    int c   = r / 640;
    int tap = (r % 640) / 128;
    int ic  = r % 128;
    wb[r] = f2bf(w[(c*128 + ic)*5 + tap]);
}

// ---------------- fused LN + GEMM (K=128, N=256), bf16 out, 2 strips/wave ------------
// Operand-swapped MFMA: lane cl owns output row t directly. Stores per-row (mu,rs).
template<typename TA>
__global__ __launch_bounds__(512, 2) void lngemm2(
    const TA* __restrict__ A,          // [BT,128] fp32 or bf16
    const bf16* __restrict__ Bt,       // [256][128] g-folded
    const float* __restrict__ Svec, const float* __restrict__ bvec,  // [256]
    bf16* __restrict__ outB,           // [BT,256]
    float2* __restrict__ munrs)        // [BT]
{
    __shared__ bf16 Bs[256*136];       // 69632 B (+8 pad per row)
    __shared__ float Sl[256], bl[256];

    int tid = threadIdx.x;
    #pragma unroll
    for (int it = 0; it < 8; ++it) {
        int f = it*512 + tid;
        int n = f >> 4, kk = (f & 15)*8;
        *(bf16x8*)&Bs[n*136 + kk] = *(const bf16x8*)(Bt + n*128 + kk);
    }
    if (tid < 256) { Sl[tid] = Svec[tid]; bl[tid] = bvec[tid]; }
    __syncthreads();

    int wid = tid >> 6, lane = tid & 63;
    int quad = lane >> 4, cl = lane & 15;
    int s0 = blockIdx.x*16 + wid*2;
    size_t row0 = (size_t)s0*16 + cl;          // strip p -> row0 + p*16

    bf16x8 af[2][4];
    float mu[2], rs[2], mr[2];
    #pragma unroll
    for (int p = 0; p < 2; ++p) {
        size_t row = row0 + (size_t)p*16;
        float sm = 0.f, sq = 0.f;
        if constexpr (sizeof(TA) == 2) {
            const bf16* ar = (const bf16*)A + row*128;
            #pragma unroll
            for (int ks = 0; ks < 4; ++ks) {
                af[p][ks] = *(const bf16x8*)(ar + quad*8 + ks*32);
                union { bf16x8 v; unsigned int u[4]; } aa; aa.v = af[p][ks];
                #pragma unroll
                for (int jp = 0; jp < 4; ++jp) {
                    float2 vv = upk(aa.u[jp]);
                    sm += vv.x + vv.y;
                    sq += vv.x*vv.x + vv.y*vv.y;
                }
            }
        } else {
            const float* ar = (const float*)A + row*128;
            #pragma unroll
            for (int ks = 0; ks < 4; ++ks) {
                float4 f0 = *(const float4*)(ar + quad*8 + ks*32);
                float4 f1 = *(const float4*)(ar + quad*8 + ks*32 + 4);
                sm += f0.x + f0.y + f0.z + f0.w + f1.x + f1.y + f1.z + f1.w;
                sq += f0.x*f0.x + f0.y*f0.y + f0.z*f0.z + f0.w*f0.w
                    + f1.x*f1.x + f1.y*f1.y + f1.z*f1.z + f1.w*f1.w;
                af[p][ks] = pack8f(f0, f1);
            }
        }
        sm += __shfl_xor(sm, 16); sm += __shfl_xor(sm, 32);
        sq += __shfl_xor(sq, 16); sq += __shfl_xor(sq, 32);
        mu[p] = sm * (1.f/128.f);
        rs[p] = rsqrtf(sq*(1.f/128.f) - mu[p]*mu[p] + 1e-5f);
        mr[p] = mu[p]*rs[p];
        if (quad == 0) munrs[row] = make_float2(mu[p], rs[p]);
    }

    #pragma unroll
    for (int g = 0; g < 4; ++g) {
        f32x4 acc0[4] = {}, acc1[4] = {};
        #pragma unroll
        for (int t4 = 0; t4 < 4; ++t4) {
            const bf16* wrp = &Bs[(((g*4+t4)*16) + cl)*136 + quad*8];
            #pragma unroll
            for (int ks = 0; ks < 4; ++ks) {
                bf16x8 w = *(const bf16x8*)(wrp + ks*32);
                acc0[t4] = __builtin_amdgcn_mfma_f32_16x16x32_bf16(w, af[0][ks], acc0[t4], 0, 0, 0);
                acc1[t4] = __builtin_amdgcn_mfma_f32_16x16x32_bf16(w, af[1][ks], acc1[t4], 0, 0, 0);
            }
        }
        #pragma unroll
        for (int t4 = 0; t4 < 4; ++t4) {
            int n0 = (g*4+t4)*16 + quad*4;
            float4 S4 = *(const float4*)&Sl[n0];
            float4 b4 = *(const float4*)&bl[n0];
            float4 o;
            o.x = rs[0]*acc0[t4][0] - mr[0]*S4.x + b4.x;
            o.y = rs[0]*acc0[t4][1] - mr[0]*S4.y + b4.y;
            o.z = rs[0]*acc0[t4][2] - mr[0]*S4.z + b4.z;
            o.w = rs[0]*acc0[t4][3] - mr[0]*S4.w + b4.w;
            *(uint2*)(outB + row0*256 + n0) = make_uint2(pkpair(o.x, o.y), pkpair(o.z, o.w));
            o.x = rs[1]*acc1[t4][0] - mr[1]*S4.x + b4.x;
            o.y = rs[1]*acc1[t4][1] - mr[1]*S4.y + b4.y;
            o.z = rs[1]*acc1[t4][2] - mr[1]*S4.z + b4.z;
            o.w = rs[1]*acc1[t4][3] - mr[1]*S4.w + b4.w;
            *(uint2*)(outB + (row0+16)*256 + n0) = make_uint2(pkpair(o.x, o.y), pkpair(o.z, o.w));
        }
    }
}

// ---------------- GEMM K=256 N=128 (bf16 A), 2 strips/wave, scan-fix + ud epilogue ---
// A-load applies the scan fix on-the-fly (xs += a^{j+1}*carry_in), then
// out = resid + acc + (resid-mu)*rs*gd + bd.
// bf16 path: resid loads hoisted BEFORE the MFMA loop (latency hidden under 128 MFMAs;
// alias-safe: each element is read-then-written by the same thread only).
template<typename TR>
__global__ __launch_bounds__(512, 2) void gemm2s(
    const bf16* __restrict__ A,        // [BT,256]
    const bf16* __restrict__ Bt,       // [128][256]
    bf16* out,                         // [BT,128] (may alias resid, same-elem r-then-w)
    const TR* resid,                   // [BT,128]
    const float2* __restrict__ munrs,
    const float* __restrict__ gdp, const float* __restrict__ bdp,
    const float2* __restrict__ carry,  // [NCHK][B][128] exclusive chunk prefix
    const float2* __restrict__ apow)   // [64][128] a^(j+1)
{
    __shared__ bf16 Bs[128*264];       // 67584 B
    __shared__ float gdl[128], bdl[128];

    int tid = threadIdx.x;
    #pragma unroll
    for (int it = 0; it < 8; ++it) {
        int f = it*512 + tid;
        int n = f >> 5, kk = (f & 31)*8;
        *(bf16x8*)&Bs[n*264 + kk] = *(const bf16x8*)(Bt + n*256 + kk);
    }
    if (tid < 128) { gdl[tid] = gdp[tid]; bdl[tid] = bdp[tid]; }
    __syncthreads();

    int wid = tid >> 6, lane = tid & 63;
    int quad = lane >> 4, cl = lane & 15;
    int s0 = blockIdx.x*16 + wid*2;
    size_t row0 = (size_t)s0*16 + cl;

    bf16x8 af[2][8];
    float mu[2], rs[2];
    #pragma unroll
    for (int p = 0; p < 2; ++p) {
        size_t row = row0 + (size_t)p*16;
        float2 m2 = munrs[row]; mu[p] = m2.x; rs[p] = m2.y;
        const bf16* ar = A + row*256 + quad*8;
        int b  = (int)(row >> 12);
        int tp = (int)(row & 4095);
        int cc = tp >> 6, j = tp & 63;
        const float2* cin = carry + (size_t)cc*(BATCH*NST) + (size_t)b*NST;
        const float2* ap  = apow + (size_t)j*128;
        #pragma unroll
        for (int ks = 0; ks < 8; ++ks) {
            union { bf16x8 v; unsigned int u[4]; } t;
            t.v = *(const bf16x8*)(ar + ks*32);
            int n0 = quad*4 + ks*16;           // complex index of t.u[0]
            #pragma unroll
            for (int jp = 0; jp < 4; ++jp) {
                float2 v  = upk(t.u[jp]);
                float2 ad = cmul2(ap[n0+jp], cin[n0+jp]);
                t.u[jp] = pk(make_float2(v.x + ad.x, v.y + ad.y));
            }
            af[p][ks] = t.v;
        }
    }

    // hoist resid loads (bf16 path) -- latency hides under the MFMA loop
    ushort4 rvh[2][8];
    if constexpr (sizeof(TR) == 2) {
        #pragma unroll
        for (int p = 0; p < 2; ++p)
            #pragma unroll
            for (int nt = 0; nt < 8; ++nt)
                rvh[p][nt] = *(const ushort4*)((const bf16*)resid
                               + (row0 + (size_t)p*16)*128 + nt*16 + quad*4);
    }

    #pragma unroll
    for (int nt = 0; nt < 8; ++nt) {
        const bf16* wrp = &Bs[(nt*16 + cl)*264 + quad*8];
        f32x4 a0 = {}, a1 = {};
        #pragma unroll
        for (int ks = 0; ks < 8; ++ks) {
            bf16x8 w = *(const bf16x8*)(wrp + ks*32);
            a0 = __builtin_amdgcn_mfma_f32_16x16x32_bf16(w, af[0][ks], a0, 0, 0, 0);
            a1 = __builtin_amdgcn_mfma_f32_16x16x32_bf16(w, af[1][ks], a1, 0, 0, 0);
        }
        int n0 = nt*16 + quad*4;
        float4 g4 = *(const float4*)&gdl[n0];
        float4 b4 = *(const float4*)&bdl[n0];
        #pragma unroll
        for (int p = 0; p < 2; ++p) {
            f32x4 ac = p ? a1 : a0;
            size_t oidx = (row0 + (size_t)p*16)*128 + n0;
            float4 rv;
            if constexpr (sizeof(TR) == 2) {
                ushort4 u4 = rvh[p][nt];
                rv = make_float4(bf2f(u4.x), bf2f(u4.y), bf2f(u4.z), bf2f(u4.w));
            } else {
                rv = *(const float4*)((const float*)resid + oidx);
            }
            float4 o;
            o.x = rv.x + ac[0] + (rv.x - mu[p])*rs[p]*g4.x + b4.x;
            o.y = rv.y + ac[1] + (rv.y - mu[p])*rs[p]*g4.y + b4.y;
            o.z = rv.z + ac[2] + (rv.z - mu[p])*rs[p]*g4.z + b4.z;
            o.w = rv.w + ac[3] + (rv.w - mu[p])*rs[p]*g4.w + b4.w;
            *(uint2*)(out + oidx) = make_uint2(pkpair(o.x, o.y), pkpair(o.z, o.w));
        }
    }
}

// ---------------- fused MLP sub-block: LN + W1 + gelu + W2 + bias + resid ------------
// 1 strip/wave (1024-thr blocks: hard VGPR ceiling is 64-128 -> 2-strip spills).
// W1 rows are sigma-permuted (prep_w1) so GEMM1's packed output hp is byte-identical
// to GEMM2's B-operand fragments: no cross-lane bridge at all. (HW-verified R3.)
__global__ __launch_bounds__(1024, 2) void mlp_fused(
    const bf16* X,                     // [BT,128] bf16 (input, resid; aliases out)
    const bf16* __restrict__ W1t,      // [256][128] g2-folded, sigma-permuted rows
    const bf16* __restrict__ W2t,      // [128][256]
    const float* __restrict__ S1v, const float* __restrict__ b1v,  // [256] true-f order
    const float* __restrict__ b2v,     // [128]
    bf16* out)                         // [BT,128] == X (same-elem read-then-write)
{
    __shared__ bf16 As1[256*136];      // 69632 B
    __shared__ bf16 Bs2[128*264];      // 67584 B
    __shared__ float S1l[256], b1l[256], b2l[128];

    int tid = threadIdx.x;
    #pragma unroll
    for (int it = 0; it < 4; ++it) {
        int f = it*1024 + tid;
        int n = f >> 4, kk = (f & 15)*8;
        *(bf16x8*)&As1[n*136 + kk] = *(const bf16x8*)(W1t + n*128 + kk);
    }
    #pragma unroll
    for (int it = 0; it < 4; ++it) {
        int f = it*1024 + tid;
        int n = f >> 5, kk = (f & 31)*8;
        *(bf16x8*)&Bs2[n*264 + kk] = *(const bf16x8*)(W2t + n*256 + kk);
    }
    if (tid < 256)      { S1l[tid] = S1v[tid]; b1l[tid] = b1v[tid]; }
    else if (tid < 384) { int h = tid - 256; b2l[h] = b2v[h]; }
    __syncthreads();

    int wid = tid >> 6, lane = tid & 63;
    int quad = lane >> 4, cl = lane & 15;
    int s = blockIdx.x*16 + wid;
    size_t row = (size_t)s*16 + cl;

    // X row: LN stats + bf16 frags
    const bf16* ar = X + row*128;
    bf16x8 af[4];
    float sm = 0.f, sq = 0.f;
    #pragma unroll
    for (int ks = 0; ks < 4; ++ks) {
        af[ks] = *(const bf16x8*)(ar + quad*8 + ks*32);
        union { bf16x8 v; unsigned int u[4]; } aa; aa.v = af[ks];
        #pragma unroll
        for (int jp = 0; jp < 4; ++jp) {
            float2 vv = upk(aa.u[jp]);
            sm += vv.x + vv.y;
            sq += vv.x*vv.x + vv.y*vv.y;
        }
    }
    sm += __shfl_xor(sm, 16); sm += __shfl_xor(sm, 32);
    sq += __shfl_xor(sq, 16); sq += __shfl_xor(sq, 32);
    float mu = sm * (1.f/128.f);
    float rs = rsqrtf(sq*(1.f/128.f) - mu*mu + 1e-5f);
    float mr = mu*rs;

    // GEMM1 (K=128) + LN-affine + gelu + pack; hp == GEMM2 A-frags by sigma-construction
    union { unsigned int u[16][2]; bf16x8 v[8]; } hp;
    #pragma unroll
    for (int half = 0; half < 2; ++half) {
        f32x4 acc[8] = {};
        #pragma unroll
        for (int nt = 0; nt < 8; ++nt) {
            const bf16* wrp = &As1[(((half*8+nt)*16) + cl)*136 + quad*8];
            #pragma unroll
            for (int ks = 0; ks < 4; ++ks)
                acc[nt] = __builtin_amdgcn_mfma_f32_16x16x32_bf16(
                              *(const bf16x8*)(wrp + ks*32), af[ks], acc[nt], 0, 0, 0);
        }
        #pragma unroll
        for (int nt = 0; nt < 8; ++nt) {
            int NT = half*8 + nt;
            // true-f base of acc regs: f = 32*(NT>>1) + 8*quad + 4*(NT&1) + r
            int fb = ((NT >> 1) << 5) + (quad << 3) + ((NT & 1) << 2);
            float4 S4 = *(const float4*)&S1l[fb];
            float4 b4 = *(const float4*)&b1l[fb];
            float4 o;
            o.x = gelu_f(rs*acc[nt][0] - mr*S4.x + b4.x);
            o.y = gelu_f(rs*acc[nt][1] - mr*S4.y + b4.y);
            o.z = gelu_f(rs*acc[nt][2] - mr*S4.z + b4.z);
            o.w = gelu_f(rs*acc[nt][3] - mr*S4.w + b4.w);
            hp.u[NT][0] = pkpair(o.x, o.y);
            hp.u[NT][1] = pkpair(o.z, o.w);
        }
    }

    // GEMM2 (K=256): B-operand = hp.v directly (no bridge)
    #pragma unroll
    for (int nt = 0; nt < 8; ++nt) {
        const bf16* wrp = &Bs2[(nt*16 + cl)*264 + quad*8];
        f32x4 a0 = {};
        #pragma unroll
        for (int ks = 0; ks < 8; ++ks) {
            bf16x8 w = *(const bf16x8*)(wrp + ks*32);
            a0 = __builtin_amdgcn_mfma_f32_16x16x32_bf16(w, hp.v[ks], a0, 0, 0, 0);
        }
        int n0 = nt*16 + quad*4;
        size_t oidx = row*128 + n0;
        float4 b4 = *(const float4*)&b2l[n0];
        ushort4 u4 = *(const ushort4*)(X + oidx);   // resid (same-elem read-then-write)
        float4 o;
        o.x = a0[0] + b4.x + bf2f(u4.x);
        o.y = a0[1] + b4.y + bf2f(u4.y);
        o.z = a0[2] + b4.z + bf2f(u4.z);
        o.w = a0[3] + b4.w + bf2f(u4.w);
        *(uint2*)(out + oidx) = make_uint2(pkpair(o.x, o.y), pkpair(o.z, o.w));
    }
}

// ---------------- chunked scan on bf16-pair xs: x_t = a*x_{t-1} + Bu_t ---------------
// Local pass only; cross-chunk fix is fused into gemm2s. 2 states/thread (uint2).
// Software-pipelined: v[j+1] prefetched before consuming v[j] -- the load address is
// independent of the recurrence, so only the ~6-cyc VALU chain stays critical.
__global__ __launch_bounds__(256) void scan_local(uint2* __restrict__ xs,
                                                  const float4* __restrict__ coefs,
                                                  float2* __restrict__ carry)
{
    int flat = blockIdx.x*256 + threadIdx.x;  // 2^17
    int n2 = flat & 63;                        // handles states 2*n2, 2*n2+1
    int b = (flat >> 6) & 31;
    int c = flat >> 11;
    float4 cf0 = coefs[2*n2], cf1 = coefs[2*n2+1];
    float2 a0 = make_float2(cf0.x, cf0.y);
    float2 a1 = make_float2(cf1.x, cf1.y);
    uint2* base = xs + ((size_t)(b*TSEQ + c*LC))*64 + n2;
    float2 x0 = make_float2(0.f, 0.f), x1 = make_float2(0.f, 0.f);
    uint2 v = base[0];
    #pragma unroll 4
    for (int j = 0; j < LC; ++j) {
        uint2 vc = v;
        if (j + 1 < LC) v = base[(size_t)(j+1)*64];
        float2 v0 = upk(vc.x), v1 = upk(vc.y);
        x0 = make_float2(a0.x*x0.x - a0.y*x0.y + v0.x, a0.x*x0.y + a0.y*x0.x + v0.y);
        x1 = make_float2(a1.x*x1.x - a1.y*x1.y + v1.x, a1.x*x1.y + a1.y*x1.x + v1.y);
        base[(size_t)j*64] = make_uint2(pk(x0), pk(x1));
    }
    carry[c*(BATCH*NST) + b*NST + 2*n2]   = x0;
    carry[c*(BATCH*NST) + b*NST + 2*n2+1] = x1;
}

__global__ void scan_carry(float2* __restrict__ carry, const float4* __restrict__ coefs)
{
    int flat = blockIdx.x*256 + threadIdx.x;  // 4096 = B*N
    int n = flat & 127;
    float4 cf = coefs[n];
    float2 aL = make_float2(cf.z, cf.w);
    float2 x = make_float2(0.f, 0.f);
    for (int c = 0; c < NCHK; ++c) {
        float2* p = carry + c*(BATCH*NST) + flat;
        float2 v = *p;
        *p = x;                                // exclusive prefix
        x = make_float2(aL.x*x.x - aL.y*x.y + v.x, aL.x*x.y + aL.y*x.x + v.y);
    }
}

// ---------------- conv1: bf16 in, implicit-im2col MFMA (operand-swapped), bf16 out ----
__global__ __launch_bounds__(256, 4) void conv1_mfma(
    const bf16* __restrict__ X,
    const bf16* __restrict__ wB,    // [128][640]
    const float* __restrict__ bias,
    bf16* __restrict__ out,         // [B*Lout][128]
    int Tin, int Lout)
{
    __shared__ bf16 As[128][72];
    __shared__ bf16 Bs[128][72];
    int tid  = threadIdx.x;
    int lane = tid & 63;
    int wave = tid >> 6;
    int wm = wave >> 1, wn = wave & 1;
    int quad = lane >> 4, cl = lane & 15;
    int row0 = blockIdx.x * 128;
    int b  = row0 / Lout;
    int l0 = row0 % Lout;
    const bf16* Xb = X + (size_t)b*Tin*128;

    f32x4 acc[4][4] = {};

    for (int k0 = 0; k0 < 640; k0 += 64) {
        int tap = k0 / 128;
        int icb = k0 % 128;
        #pragma unroll
        for (int it = 0; it < 4; ++it) {
            int idx = it*256 + tid;
            int r = idx >> 3, kof = (idx & 7) * 8;
            int t = 2*(l0 + r) - 2 + tap;
            bf16x8 z = {0,0,0,0,0,0,0,0};
            if (t >= 0 && t < Tin) z = *(const bf16x8*)(Xb + (size_t)t*128 + icb + kof);
            *(bf16x8*)&As[r][kof] = z;
        }
        #pragma unroll
        for (int it = 0; it < 4; ++it) {
            int idx = it*256 + tid;
            int n = idx >> 3, kof = (idx & 7) * 8;
            *(bf16x8*)&Bs[n][kof] = *(const bf16x8*)(wB + (size_t)n*640 + k0 + kof);
        }
        __syncthreads();
        #pragma unroll
        for (int kk = 0; kk < 64; kk += 32) {
            bf16x8 af[4], bfr[4];
            #pragma unroll
            for (int i = 0; i < 4; ++i)
                af[i] = *(const bf16x8*)&As[wm*64 + i*16 + cl][kk + quad*8];
            #pragma unroll
            for (int j = 0; j < 4; ++j)
                bfr[j] = *(const bf16x8*)&Bs[wn*64 + j*16 + cl][kk + quad*8];
            #pragma unroll
            for (int i = 0; i < 4; ++i)
                #pragma unroll
                for (int j = 0; j < 4; ++j)
                    acc[i][j] = __builtin_amdgcn_mfma_f32_16x16x32_bf16(
                                    bfr[j], af[i], acc[i][j], 0, 0, 0);
        }
        __syncthreads();
    }

    #pragma unroll
    for (int i = 0; i < 4; ++i) {
        int grow = row0 + wm*64 + i*16 + cl;
        #pragma unroll
        for (int j = 0; j < 4; ++j) {
            int gcol = wn*64 + j*16 + quad*4;
            float4 bv = *(const float4*)(bias + gcol);
            float4 t;
            t.x = fmaxf(acc[i][j][0] + bv.x, 0.f); t.y = fmaxf(acc[i][j][1] + bv.y, 0.f);
            t.z = fmaxf(acc[i][j][2] + bv.z, 0.f); t.w = fmaxf(acc[i][j][3] + bv.w, 0.f);
            uint2 pu = make_uint2(pkpair(t.x, t.y), pkpair(t.z, t.w));
            *(uint2*)(out + (size_t)grow*128 + gcol) = pu;
        }
    }
}

// ---------------- conv2 (bf16 in) + fused relu + avg pool (operand-swapped) ----------
__global__ __launch_bounds__(256, 4) void conv2_pool(
    const bf16* __restrict__ X,     // [B][Tin][128]
    const bf16* __restrict__ wB,    // [128][640]
    const float* __restrict__ bias,
    float* __restrict__ outp,       // [B][128][64]
    int Tin, int Lout)
{
    __shared__ bf16 As[128][72];
    __shared__ bf16 Bs[128][72];
    int tid  = threadIdx.x;
    int lane = tid & 63;
    int wave = tid >> 6;
    int wm = wave >> 1, wn = wave & 1;
    int quad = lane >> 4, cl = lane & 15;
    int row0 = blockIdx.x * 128;
    int b  = row0 / Lout;
    int l0 = row0 % Lout;
    int d0 = l0 / 16;
    const bf16* Xb = X + (size_t)b*Tin*128;

    f32x4 acc[4][4] = {};

    for (int k0 = 0; k0 < 640; k0 += 64) {
        int tap = k0 / 128;
        int icb = k0 % 128;
        #pragma unroll
        for (int it = 0; it < 4; ++it) {
            int idx = it*256 + tid;
            int r = idx >> 3, kof = (idx & 7) * 8;
            int t = 2*(l0 + r) - 2 + tap;
            bf16x8 z = {0,0,0,0,0,0,0,0};
            if (t >= 0 && t < Tin) z = *(const bf16x8*)(Xb + (size_t)t*128 + icb + kof);
            *(bf16x8*)&As[r][kof] = z;
        }
        #pragma unroll
        for (int it = 0; it < 4; ++it) {
            int idx = it*256 + tid;
            int n = idx >> 3, kof = (idx & 7) * 8;
            *(bf16x8*)&Bs[n][kof] = *(const bf16x8*)(wB + (size_t)n*640 + k0 + kof);
        }
        __syncthreads();
        #pragma unroll
        for (int kk = 0; kk < 64; kk += 32) {
            bf16x8 af[4], bfr[4];
            #pragma unroll
            for (int i = 0; i < 4; ++i)
                af[i] = *(const bf16x8*)&As[wm*64 + i*16 + cl][kk + quad*8];
            #pragma unroll
            for (int j = 0; j < 4; ++j)
                bfr[j] = *(const bf16x8*)&Bs[wn*64 + j*16 + cl][kk + quad*8];
            #pragma unroll
            for (int i = 0; i < 4; ++i)
                #pragma unroll
                for (int j = 0; j < 4; ++j)
                    acc[i][j] = __builtin_amdgcn_mfma_f32_16x16x32_bf16(
                                    bfr[j], af[i], acc[i][j], 0, 0, 0);
        }
        __syncthreads();
    }

    #pragma unroll
    for (int j = 0; j < 4; ++j) {
        int gcol = wn*64 + j*16 + quad*4;
        float4 bv = *(const float4*)(bias + gcol);
        #pragma unroll
        for (int i = 0; i < 4; ++i) {
            float4 sp;
            sp.x = fmaxf(acc[i][j][0] + bv.x, 0.f);
            sp.y = fmaxf(acc[i][j][1] + bv.y, 0.f);
            sp.z = fmaxf(acc[i][j][2] + bv.z, 0.f);
            sp.w = fmaxf(acc[i][j][3] + bv.w, 0.f);
            #pragma unroll
            for (int off = 1; off <= 8; off <<= 1) {
                sp.x += __shfl_xor(sp.x, off);
                sp.y += __shfl_xor(sp.y, off);
                sp.z += __shfl_xor(sp.z, off);
                sp.w += __shfl_xor(sp.w, off);
            }
            if (cl == 0) {
                int d = d0 + wm*4 + i;
                float* op = outp + (size_t)b*8192 + (size_t)gcol*64 + d;
                op[0]   = sp.x * (1.f/16.f);
                op[64]  = sp.y * (1.f/16.f);
                op[128] = sp.z * (1.f/16.f);
                op[192] = sp.w * (1.f/16.f);
            }
        }
    }
}

extern "C" void kernel_launch(void* const* d_in, const int* in_sizes, int n_in,
                              void* d_out, int out_size, void* d_ws, size_t ws_size,
                              hipStream_t stream)
{
    (void)in_sizes; (void)n_in; (void)out_size; (void)ws_size;
    const float* x_in    = (const float*)d_in[0];
    const float* ln1_g   = (const float*)d_in[1];
    const float* ln1_b   = (const float*)d_in[2];
    const float* ln2_g   = (const float*)d_in[3];
    const float* ln2_b   = (const float*)d_in[4];
    const float* Lam_re  = (const float*)d_in[5];
    const float* Lam_im  = (const float*)d_in[6];
    const float* B_re    = (const float*)d_in[7];
    const float* B_im    = (const float*)d_in[8];
    const float* C_re    = (const float*)d_in[9];
    const float* C_im    = (const float*)d_in[10];
    const float* D_skip  = (const float*)d_in[11];
    const float* log_step= (const float*)d_in[12];
    const float* W1      = (const float*)d_in[13];
    const float* b1      = (const float*)d_in[14];
    const float* W2      = (const float*)d_in[15];
    const float* b2      = (const float*)d_in[16];
    const float* conv1_w = (const float*)d_in[17];
    const float* conv1_b = (const float*)d_in[18];
    const float* conv2_w = (const float*)d_in[19];
    const float* conv2_b = (const float*)d_in[20];
    float* out = (float*)d_out;

    // Workspace (~122 MB): Xbf bf16 32MB | Cbuf bf16 [BT,256] 64MB | Cv1 bf16 16MB
    //                      | munrs 1MB | params+carry+apow ~4MB
    char* ws = (char*)d_ws;
    bf16*   Xbf    = (bf16*) (ws);
    bf16*   Cbuf   = (bf16*) (ws + (size_t)33554432);
    bf16*   Cv1    = (bf16*) (ws + (size_t)100663296);
    float2* munrs  = (float2*)(ws + (size_t)117440512);
    char*   wreg   = ws + (size_t)118489088;
    bf16*   Wbu_bf = (bf16*)(wreg);                  // 131072
    bf16*   Wc_bf  = (bf16*)(wreg + 131072);         // 131072
    bf16*   W1_bf  = (bf16*)(wreg + 262144);         // 131072
    bf16*   W2_bf  = (bf16*)(wreg + 393216);         // 131072
    float*  Sb     = (float*)(wreg + 524288);        // 2048
    float*  biasb  = (float*)(wreg + 526336);        // 2048
    float*  S1     = (float*)(wreg + 528384);        // 2048
    float*  bias1p = (float*)(wreg + 530432);        // 2048
    float*  gd     = (float*)(wreg + 532480);        // 1024
    float*  bd     = (float*)(wreg + 533504);        // 1024
    float4* coefs  = (float4*)(wreg + 534528);       // 4096
    bf16*   wB1    = (bf16*)(wreg + 538624);         // 163840
    bf16*   wB2    = (bf16*)(wreg + 702464);         // 163840
    float2* carry  = (float2*)(wreg + 866304);       // 2 MB
    float2* apow   = (float2*)(wreg + 2963456);      // 2*64*128*8 = 131072

    prep_s5<<<2, 128, 0, stream>>>(Lam_re, Lam_im, B_re, B_im, C_re, C_im, log_step,
                                   ln1_g, ln1_b, D_skip,
                                   Wbu_bf, Wc_bf, Sb, biasb, gd, bd, coefs, apow);
    prep_w1<<<2, 256, 0, stream>>>(W1, b1, ln2_g, ln2_b, W1_bf, S1, bias1p);
    prep_w2<<<2, 128, 0, stream>>>(W2, W2_bf);
    prep_wB<<<640, 256, 0, stream>>>(conv1_w, conv2_w, wB1, wB2);

    for (int i = 0; i < 2; ++i) {
        // ---- S5 sub-block: LN+Wbu (Bu + munrs), local scan + carry, Wc+fix+resid+ud ----
        if (i == 0)
            lngemm2<float><<<512, 512, 0, stream>>>(
                x_in, Wbu_bf, Sb, biasb, Cbuf, munrs);
        else
            lngemm2<bf16><<<512, 512, 0, stream>>>(
                Xbf, Wbu_bf + 32768, Sb + 256, biasb + 256, Cbuf, munrs);
        scan_local<<<512, 256, 0, stream>>>((uint2*)Cbuf, coefs + i*NST, carry);
        scan_carry<<<16, 256, 0, stream>>>(carry, coefs + i*NST);
        if (i == 0)
            gemm2s<float><<<512, 512, 0, stream>>>(
                Cbuf, Wc_bf, Xbf, x_in, munrs, gd, bd, carry, apow);
        else
            gemm2s<bf16><<<512, 512, 0, stream>>>(
                Cbuf, Wc_bf + 32768, Xbf, Xbf, munrs, gd + 128, bd + 128,
                carry, apow + 64*128);
        // ---- MLP sub-block: single fused kernel (LN+W1+gelu+W2+bias+resid) ----
        mlp_fused<<<512, 1024, 0, stream>>>(
            Xbf, W1_bf + (size_t)i*32768, W2_bf + (size_t)i*32768,
            S1 + i*256, bias1p + i*256, b2 + i*HD, Xbf);
    }

    // ---- head: conv1 (Xbf -> bf16) -> conv2+pool (-> d_out) ----
    conv1_mfma<<<512, 256, 0, stream>>>(Xbf, wB1, conv1_b, Cv1, 4096, 2048);
    conv2_pool<<<256, 256, 0, stream>>>(Cv1, wB2, conv2_b, out, 2048, 1024);
}